// Round 1
// baseline (717.664 us; speedup 1.0000x reference)
//
#include <hip/hip_runtime.h>
#include <hip/hip_bf16.h>
#include <math.h>

#define NN 50000
#define EE 800000
#define OBSD 256
#define HD 128
#define GG 1024
#define NHEADS 4
#define ACTD 10
#define LN_EPS 1e-5f
#define NCHUNKS 49   // ceil(50000/1024)

__device__ __forceinline__ float4 ld4(const float* p){ return *(const float4*)p; }

// ---------------- K1: x = tanh(obs @ emb_w + emb_b)  [N,256]x[256,128] ----------------
__global__ __launch_bounds__(256) void k_emb(const float* __restrict__ obs,
    const float* __restrict__ W, const float* __restrict__ bias,
    float* __restrict__ x){
  __shared__ float As[16][68];    // k-major A tile, 64 rows
  __shared__ float Bs[16][128];
  int tid = threadIdx.x, blk = blockIdx.x;
  int arow = tid>>2, kb=(tid&3)*4;
  int wr = tid>>4, wc = (tid&15)*8;
  int ty = tid>>4, tx = tid&15;
  float acc[4][8];
  #pragma unroll
  for (int i=0;i<4;++i)
    #pragma unroll
    for (int j=0;j<8;++j) acc[i][j]=0.f;
  int agr = blk*64 + arow;
  for (int kt=0; kt<16; ++kt){
    int k0 = kt*16;
    float4 av = (agr<NN)? ld4(&obs[agr*OBSD + k0 + kb]) : make_float4(0.f,0.f,0.f,0.f);
    As[kb+0][arow]=av.x; As[kb+1][arow]=av.y; As[kb+2][arow]=av.z; As[kb+3][arow]=av.w;
    *(float4*)&Bs[wr][wc]   = ld4(&W[(k0+wr)*HD+wc]);
    *(float4*)&Bs[wr][wc+4] = ld4(&W[(k0+wr)*HD+wc+4]);
    __syncthreads();
    #pragma unroll
    for (int kk=0;kk<16;++kk){
      float4 a  = *(const float4*)&As[kk][ty*4];
      float4 b0 = *(const float4*)&Bs[kk][tx*8];
      float4 b1 = *(const float4*)&Bs[kk][tx*8+4];
      float aa[4]={a.x,a.y,a.z,a.w};
      float bb[8]={b0.x,b0.y,b0.z,b0.w,b1.x,b1.y,b1.z,b1.w};
      #pragma unroll
      for (int i=0;i<4;++i)
        #pragma unroll
        for (int j=0;j<8;++j) acc[i][j] = fmaf(aa[i], bb[j], acc[i][j]);
    }
    __syncthreads();
  }
  int cb0 = tx*8;
  float b8[8];
  #pragma unroll
  for (int j=0;j<8;++j) b8[j]=bias[cb0+j];
  #pragma unroll
  for (int i=0;i<4;++i){
    int gr = blk*64 + ty*4 + i;
    if (gr<NN){
      float4 o0 = make_float4(tanhf(acc[i][0]+b8[0]), tanhf(acc[i][1]+b8[1]),
                              tanhf(acc[i][2]+b8[2]), tanhf(acc[i][3]+b8[3]));
      float4 o1 = make_float4(tanhf(acc[i][4]+b8[4]), tanhf(acc[i][5]+b8[5]),
                              tanhf(acc[i][6]+b8[6]), tanhf(acc[i][7]+b8[7]));
      *(float4*)&x[gr*HD+cb0]   = o0;
      *(float4*)&x[gr*HD+cb0+4] = o1;
    }
  }
}

// ---------------- K2: xl = x@Wl, xr = x@Wr (no bias/act) ----------------
__global__ __launch_bounds__(256) void k_lift(const float* __restrict__ x,
    const float* __restrict__ Wl, const float* __restrict__ Wr,
    float* __restrict__ xl, float* __restrict__ xr){
  __shared__ float As[16][68];
  __shared__ float BL[16][128];
  __shared__ float BR[16][128];
  int tid=threadIdx.x, blk=blockIdx.x;
  int arow=tid>>2, kb=(tid&3)*4;
  int wr_=tid>>4, wc=(tid&15)*8;
  int ty=tid>>4, tx=tid&15;
  float accL[4][8], accR[4][8];
  #pragma unroll
  for (int i=0;i<4;++i)
    #pragma unroll
    for (int j=0;j<8;++j){ accL[i][j]=0.f; accR[i][j]=0.f; }
  int agr = blk*64 + arow;
  for (int kt=0;kt<8;++kt){
    int k0=kt*16;
    float4 av = (agr<NN)? ld4(&x[agr*HD + k0+kb]) : make_float4(0.f,0.f,0.f,0.f);
    As[kb+0][arow]=av.x; As[kb+1][arow]=av.y; As[kb+2][arow]=av.z; As[kb+3][arow]=av.w;
    *(float4*)&BL[wr_][wc]   = ld4(&Wl[(k0+wr_)*HD+wc]);
    *(float4*)&BL[wr_][wc+4] = ld4(&Wl[(k0+wr_)*HD+wc+4]);
    *(float4*)&BR[wr_][wc]   = ld4(&Wr[(k0+wr_)*HD+wc]);
    *(float4*)&BR[wr_][wc+4] = ld4(&Wr[(k0+wr_)*HD+wc+4]);
    __syncthreads();
    #pragma unroll
    for (int kk=0;kk<16;++kk){
      float4 a   = *(const float4*)&As[kk][ty*4];
      float4 bl0 = *(const float4*)&BL[kk][tx*8];
      float4 bl1 = *(const float4*)&BL[kk][tx*8+4];
      float4 br0 = *(const float4*)&BR[kk][tx*8];
      float4 br1 = *(const float4*)&BR[kk][tx*8+4];
      float aa[4]={a.x,a.y,a.z,a.w};
      float bb[8]={bl0.x,bl0.y,bl0.z,bl0.w,bl1.x,bl1.y,bl1.z,bl1.w};
      float cc[8]={br0.x,br0.y,br0.z,br0.w,br1.x,br1.y,br1.z,br1.w};
      #pragma unroll
      for (int i=0;i<4;++i)
        #pragma unroll
        for (int j=0;j<8;++j){
          accL[i][j] = fmaf(aa[i], bb[j], accL[i][j]);
          accR[i][j] = fmaf(aa[i], cc[j], accR[i][j]);
        }
    }
    __syncthreads();
  }
  int cb0=tx*8;
  #pragma unroll
  for (int i=0;i<4;++i){
    int gr = blk*64 + ty*4 + i;
    if (gr<NN){
      float4 l0 = make_float4(accL[i][0],accL[i][1],accL[i][2],accL[i][3]);
      float4 l1 = make_float4(accL[i][4],accL[i][5],accL[i][6],accL[i][7]);
      float4 r0 = make_float4(accR[i][0],accR[i][1],accR[i][2],accR[i][3]);
      float4 r1 = make_float4(accR[i][4],accR[i][5],accR[i][6],accR[i][7]);
      *(float4*)&xl[gr*HD+cb0]   = l0; *(float4*)&xl[gr*HD+cb0+4] = l1;
      *(float4*)&xr[gr*HD+cb0]   = r0; *(float4*)&xr[gr*HD+cb0+4] = r1;
    }
  }
}

// ---------------- CSR build ----------------
__global__ __launch_bounds__(256) void k_hist(const int* __restrict__ dst, int* __restrict__ counts){
  int i = blockIdx.x*256 + threadIdx.x;
  if (i<EE) atomicAdd(&counts[dst[i]], 1);
}

__global__ __launch_bounds__(256) void k_scanA(const int* __restrict__ counts, int* __restrict__ chunks){
  __shared__ int red[256];
  int tid=threadIdx.x;
  int base = blockIdx.x*1024 + tid*4;
  int s=0;
  #pragma unroll
  for (int j=0;j<4;++j) if (base+j<NN) s += counts[base+j];
  red[tid]=s; __syncthreads();
  for (int st=128; st>0; st>>=1){ if (tid<st) red[tid]+=red[tid+st]; __syncthreads(); }
  if (tid==0) chunks[blockIdx.x]=red[0];
}

__global__ __launch_bounds__(64) void k_scanB(int* __restrict__ chunks, int* __restrict__ rowptr){
  int lane = threadIdx.x;
  int v = (lane<NCHUNKS)? chunks[lane] : 0;
  int orig = v;
  #pragma unroll
  for (int off=1; off<64; off<<=1){
    int t = __shfl_up(v, off, 64);
    if (lane>=off) v += t;
  }
  if (lane<NCHUNKS) chunks[lane] = v - orig;
  if (lane==0) rowptr[NN] = EE;
}

__global__ __launch_bounds__(256) void k_scanC(int* __restrict__ cursor,
    const int* __restrict__ chunks, int* __restrict__ rowptr){
  __shared__ int sc[256];
  int tid=threadIdx.x;
  int base = blockIdx.x*1024 + tid*4;
  int c[4]; int ts=0;
  #pragma unroll
  for (int j=0;j<4;++j){ c[j] = (base+j<NN)? cursor[base+j] : 0; ts += c[j]; }
  sc[tid]=ts; __syncthreads();
  for (int off=1; off<256; off<<=1){
    int t = (tid>=off)? sc[tid-off] : 0;
    __syncthreads();
    sc[tid]+=t;
    __syncthreads();
  }
  int run = chunks[blockIdx.x] + sc[tid] - ts;
  #pragma unroll
  for (int j=0;j<4;++j){
    if (base+j<NN){ rowptr[base+j]=run; cursor[base+j]=run; run += c[j]; }
  }
}

__global__ __launch_bounds__(256) void k_scatter(const int* __restrict__ ei,
    int* __restrict__ cursor, int* __restrict__ col){
  int i = blockIdx.x*256 + threadIdx.x;
  if (i<EE){
    int s = ei[i], d = ei[EE+i];
    int p = atomicAdd(&cursor[d], 1);
    col[p] = s;
  }
}

// ---------------- K4: GAT aggregate, one wave per node, online softmax ----------------
__global__ __launch_bounds__(256) void k_gat(const float* __restrict__ xl,
    const float* __restrict__ xr, const int* __restrict__ rowptr,
    const int* __restrict__ col, const float* __restrict__ att,
    const float* __restrict__ gbias, float* __restrict__ intra){
  int node = blockIdx.x*4 + (threadIdx.x>>6);
  int lane = threadIdx.x & 63;
  float2 xr_d = *((const float2*)(xr + (size_t)node*HD) + lane);
  float2 att2 = *((const float2*)att + lane);
  float2 v = *((const float2*)(xl + (size_t)node*HD) + lane);
  float ax = v.x + xr_d.x; ax = ax>0.f? ax : 0.2f*ax;
  float ay = v.y + xr_d.y; ay = ay>0.f? ay : 0.2f*ay;
  float e = ax*att2.x + ay*att2.y;
  #pragma unroll
  for (int off=32; off>0; off>>=1) e += __shfl_xor(e, off, 64);
  float m = e, denom = 1.f;
  float2 acc = v;
  int p1 = rowptr[node+1];
  for (int p=rowptr[node]; p<p1; ++p){
    int s = col[p];
    float2 vs = *((const float2*)(xl + (size_t)s*HD) + lane);
    float bx = vs.x + xr_d.x; bx = bx>0.f? bx:0.2f*bx;
    float by = vs.y + xr_d.y; by = by>0.f? by:0.2f*by;
    float es = bx*att2.x + by*att2.y;
    #pragma unroll
    for (int off=32; off>0; off>>=1) es += __shfl_xor(es, off, 64);
    float nm = fmaxf(m, es);
    float scl = __expf(m-nm);
    float ww  = __expf(es-nm);
    acc.x = acc.x*scl + ww*vs.x;
    acc.y = acc.y*scl + ww*vs.y;
    denom = denom*scl + ww;
    m = nm;
  }
  float2 gb = *((const float2*)gbias + lane);
  float inv = 1.f/denom;
  float2 r;
  r.x = tanhf(acc.x*inv + gb.x);
  r.y = tanhf(acc.y*inv + gb.y);
  *((float2*)(intra + (size_t)node*HD) + lane) = r;
}

// ---------------- K5: c = intra[core]; qkv = c @ Win + b ----------------
__global__ __launch_bounds__(256) void k_qkv(const float* __restrict__ intra,
    const int* __restrict__ core, const float* __restrict__ W,
    const float* __restrict__ bias, float* __restrict__ c_out, float* __restrict__ qkv){
  __shared__ float Cs[128][36];
  __shared__ float Ws[16][132];
  int tid=threadIdx.x;
  int g0 = blockIdx.x*32;
  int cb = blockIdx.y;   // 0..2, which 128-wide column block of 384
  { int row=tid>>3, kb=(tid&7)*16;
    int src = core[g0+row];
    #pragma unroll
    for (int j4=0;j4<4;++j4){
      float4 vv = ld4(&intra[(size_t)src*HD + kb + j4*4]);
      int c0=kb+j4*4;
      Cs[c0+0][row]=vv.x; Cs[c0+1][row]=vv.y; Cs[c0+2][row]=vv.z; Cs[c0+3][row]=vv.w;
      if (cb==0) *(float4*)&c_out[(size_t)(g0+row)*HD + c0] = vv;
    }
  }
  __syncthreads();
  int ty=tid>>5, tx=tid&31, wr=tid>>4, wc=(tid&15)*8;
  float acc[4][4];
  #pragma unroll
  for (int i=0;i<4;++i)
    #pragma unroll
    for (int j=0;j<4;++j) acc[i][j]=0.f;
  for (int kt=0;kt<8;++kt){
    *(float4*)&Ws[wr][wc]   = ld4(&W[(kt*16+wr)*384 + cb*128 + wc]);
    *(float4*)&Ws[wr][wc+4] = ld4(&W[(kt*16+wr)*384 + cb*128 + wc+4]);
    __syncthreads();
    #pragma unroll
    for (int kk=0;kk<16;++kk){
      float4 a = *(const float4*)&Cs[kt*16+kk][ty*4];
      float4 b = *(const float4*)&Ws[kk][tx*4];
      float aa[4]={a.x,a.y,a.z,a.w};
      float bb[4]={b.x,b.y,b.z,b.w};
      #pragma unroll
      for (int i=0;i<4;++i)
        #pragma unroll
        for (int j=0;j<4;++j) acc[i][j] = fmaf(aa[i], bb[j], acc[i][j]);
    }
    __syncthreads();
  }
  #pragma unroll
  for (int i=0;i<4;++i){
    int g = g0 + ty*4 + i;
    #pragma unroll
    for (int j=0;j<4;++j){
      int colg = cb*128 + tx*4 + j;
      qkv[(size_t)g*384 + colg] = acc[i][j] + bias[colg];
    }
  }
}

// ---------------- K6: scores[h][q][k] = q.k / sqrt(32) ----------------
__global__ __launch_bounds__(256) void k_scores(const float* __restrict__ qkv, float* __restrict__ sc){
  __shared__ float Qs[32][68];
  __shared__ float Ks[32][68];
  int tid=threadIdx.x;
  int qt=blockIdx.x, kt=blockIdx.y, h=blockIdx.z;
  { int row=tid>>2, db=(tid&3)*8;
    float4 q0 = ld4(&qkv[(size_t)(qt*64+row)*384 + h*32 + db]);
    float4 q1 = ld4(&qkv[(size_t)(qt*64+row)*384 + h*32 + db + 4]);
    Qs[db+0][row]=q0.x; Qs[db+1][row]=q0.y; Qs[db+2][row]=q0.z; Qs[db+3][row]=q0.w;
    Qs[db+4][row]=q1.x; Qs[db+5][row]=q1.y; Qs[db+6][row]=q1.z; Qs[db+7][row]=q1.w;
    float4 k0 = ld4(&qkv[(size_t)(kt*64+row)*384 + 128 + h*32 + db]);
    float4 k1 = ld4(&qkv[(size_t)(kt*64+row)*384 + 128 + h*32 + db + 4]);
    Ks[db+0][row]=k0.x; Ks[db+1][row]=k0.y; Ks[db+2][row]=k0.z; Ks[db+3][row]=k0.w;
    Ks[db+4][row]=k1.x; Ks[db+5][row]=k1.y; Ks[db+6][row]=k1.z; Ks[db+7][row]=k1.w;
  }
  __syncthreads();
  int ty=tid>>4, tx=tid&15;
  float acc[4][4];
  #pragma unroll
  for (int i=0;i<4;++i)
    #pragma unroll
    for (int j=0;j<4;++j) acc[i][j]=0.f;
  #pragma unroll
  for (int d=0; d<32; ++d){
    float4 a = *(const float4*)&Qs[d][ty*4];
    float4 b = *(const float4*)&Ks[d][tx*4];
    float aa[4]={a.x,a.y,a.z,a.w};
    float bb[4]={b.x,b.y,b.z,b.w};
    #pragma unroll
    for (int i=0;i<4;++i)
      #pragma unroll
      for (int j=0;j<4;++j) acc[i][j] = fmaf(aa[i], bb[j], acc[i][j]);
  }
  const float scale = 0.17677669529663687f;
  #pragma unroll
  for (int i=0;i<4;++i){
    int row = qt*64+ty*4+i;
    float4 o = make_float4(acc[i][0]*scale, acc[i][1]*scale, acc[i][2]*scale, acc[i][3]*scale);
    *(float4*)&sc[((size_t)h*GG+row)*GG + kt*64 + tx*4] = o;
  }
}

// ---------------- K7: row softmax over 1024 ----------------
__global__ __launch_bounds__(256) void k_softmax(float* __restrict__ sc){
  int row = blockIdx.x*4 + (threadIdx.x>>6);
  int lane = threadIdx.x & 63;
  float* p = sc + (size_t)row*GG;
  float4 v[4];
  #pragma unroll
  for (int i=0;i<4;++i) v[i] = *(float4*)&p[lane*4 + i*256];
  float m = v[0].x;
  #pragma unroll
  for (int i=0;i<4;++i){
    m = fmaxf(m, v[i].x); m = fmaxf(m, v[i].y);
    m = fmaxf(m, v[i].z); m = fmaxf(m, v[i].w);
  }
  #pragma unroll
  for (int off=32; off>0; off>>=1) m = fmaxf(m, __shfl_xor(m, off, 64));
  float s=0.f;
  #pragma unroll
  for (int i=0;i<4;++i){
    v[i].x=__expf(v[i].x-m); v[i].y=__expf(v[i].y-m);
    v[i].z=__expf(v[i].z-m); v[i].w=__expf(v[i].w-m);
    s += v[i].x+v[i].y+v[i].z+v[i].w;
  }
  #pragma unroll
  for (int off=32; off>0; off>>=1) s += __shfl_xor(s, off, 64);
  float inv = 1.f/s;
  #pragma unroll
  for (int i=0;i<4;++i){
    v[i].x*=inv; v[i].y*=inv; v[i].z*=inv; v[i].w*=inv;
    *(float4*)&p[lane*4 + i*256] = v[i];
  }
}

// ---------------- K8: o = attn @ v ----------------
__global__ __launch_bounds__(256) void k_av(const float* __restrict__ sc,
    const float* __restrict__ qkv, float* __restrict__ ob){
  __shared__ float Ps[64][68];
  __shared__ float Vs[64][36];
  int tid=threadIdx.x;
  int qt=blockIdx.x, h=blockIdx.y;
  int ty=tid>>4, tx=tid&15;
  float acc[4][2];
  #pragma unroll
  for (int i=0;i<4;++i){ acc[i][0]=0.f; acc[i][1]=0.f; }
  for (int kt=0; kt<16; ++kt){
    { int row=tid>>2, kb=(tid&3)*16;
      const float* src = &sc[((size_t)h*GG + qt*64+row)*GG + kt*64 + kb];
      float4 a0=ld4(src), a1=ld4(src+4), a2=ld4(src+8), a3=ld4(src+12);
      Ps[kb+ 0][row]=a0.x; Ps[kb+ 1][row]=a0.y; Ps[kb+ 2][row]=a0.z; Ps[kb+ 3][row]=a0.w;
      Ps[kb+ 4][row]=a1.x; Ps[kb+ 5][row]=a1.y; Ps[kb+ 6][row]=a1.z; Ps[kb+ 7][row]=a1.w;
      Ps[kb+ 8][row]=a2.x; Ps[kb+ 9][row]=a2.y; Ps[kb+10][row]=a2.z; Ps[kb+11][row]=a2.w;
      Ps[kb+12][row]=a3.x; Ps[kb+13][row]=a3.y; Ps[kb+14][row]=a3.z; Ps[kb+15][row]=a3.w;
      int kk=tid>>2, db=(tid&3)*8;
      float4 v0 = ld4(&qkv[(size_t)(kt*64+kk)*384 + 256 + h*32 + db]);
      float4 v1 = ld4(&qkv[(size_t)(kt*64+kk)*384 + 256 + h*32 + db + 4]);
      *(float4*)&Vs[kk][db]   = v0;
      *(float4*)&Vs[kk][db+4] = v1;
    }
    __syncthreads();
    #pragma unroll
    for (int k=0;k<64;++k){
      float4 a = *(const float4*)&Ps[k][ty*4];
      float2 b = *(const float2*)&Vs[k][tx*2];
      acc[0][0]=fmaf(a.x,b.x,acc[0][0]); acc[0][1]=fmaf(a.x,b.y,acc[0][1]);
      acc[1][0]=fmaf(a.y,b.x,acc[1][0]); acc[1][1]=fmaf(a.y,b.y,acc[1][1]);
      acc[2][0]=fmaf(a.z,b.x,acc[2][0]); acc[2][1]=fmaf(a.z,b.y,acc[2][1]);
      acc[3][0]=fmaf(a.w,b.x,acc[3][0]); acc[3][1]=fmaf(a.w,b.y,acc[3][1]);
    }
    __syncthreads();
  }
  #pragma unroll
  for (int i=0;i<4;++i){
    float2 o2; o2.x=acc[i][0]; o2.y=acc[i][1];
    *(float2*)&ob[(size_t)(qt*64+ty*4+i)*HD + h*32 + tx*2] = o2;
  }
}

// ---------------- K9: h1 = LN1(c + o@Wout + b) ----------------
__global__ __launch_bounds__(256) void k_ln1(const float* __restrict__ c,
    const float* __restrict__ o, const float* __restrict__ W, const float* __restrict__ bias,
    const float* __restrict__ g, const float* __restrict__ b, float* __restrict__ h1){
  __shared__ float Os[128][36];
  __shared__ float Ws[16][132];
  __shared__ float Ss[32][132];
  __shared__ float mu_s[32], rs_s[32];
  int tid=threadIdx.x; int g0=blockIdx.x*32;
  { int row=tid>>3, kb=(tid&7)*16;
    #pragma unroll
    for (int j4=0;j4<4;++j4){
      float4 v = ld4(&o[(size_t)(g0+row)*HD + kb + j4*4]);
      int c0=kb+j4*4;
      Os[c0+0][row]=v.x; Os[c0+1][row]=v.y; Os[c0+2][row]=v.z; Os[c0+3][row]=v.w;
    }
  }
  __syncthreads();
  int ty=tid>>5, tx=tid&31, wr=tid>>4, wc=(tid&15)*8;
  float acc[4][4];
  #pragma unroll
  for (int i=0;i<4;++i)
    #pragma unroll
    for (int j=0;j<4;++j) acc[i][j]=0.f;
  for (int kt=0;kt<8;++kt){
    *(float4*)&Ws[wr][wc]   = ld4(&W[(kt*16+wr)*HD + wc]);
    *(float4*)&Ws[wr][wc+4] = ld4(&W[(kt*16+wr)*HD + wc+4]);
    __syncthreads();
    #pragma unroll
    for (int kk=0;kk<16;++kk){
      float4 a = *(const float4*)&Os[kt*16+kk][ty*4];
      float4 bb4 = *(const float4*)&Ws[kk][tx*4];
      float aa[4]={a.x,a.y,a.z,a.w};
      float bb[4]={bb4.x,bb4.y,bb4.z,bb4.w};
      #pragma unroll
      for (int i=0;i<4;++i)
        #pragma unroll
        for (int j=0;j<4;++j) acc[i][j]=fmaf(aa[i],bb[j],acc[i][j]);
    }
    __syncthreads();
  }
  #pragma unroll
  for (int i=0;i<4;++i){
    int r=ty*4+i;
    #pragma unroll
    for (int j=0;j<4;++j){
      int colg=tx*4+j;
      Ss[r][colg] = acc[i][j] + c[(size_t)(g0+r)*HD + colg] + bias[colg];
    }
  }
  __syncthreads();
  if (tid<32){
    float mu=0.f;
    for (int k=0;k<HD;++k) mu += Ss[tid][k];
    mu *= (1.f/HD);
    float var=0.f;
    for (int k=0;k<HD;++k){ float d=Ss[tid][k]-mu; var += d*d; }
    var *= (1.f/HD);
    mu_s[tid]=mu; rs_s[tid]=rsqrtf(var+LN_EPS);
  }
  __syncthreads();
  #pragma unroll
  for (int i=0;i<4;++i){
    int r=ty*4+i;
    #pragma unroll
    for (int j=0;j<4;++j){
      int colg=tx*4+j;
      h1[(size_t)(g0+r)*HD + colg] = (Ss[r][colg]-mu_s[r])*rs_s[r]*g[colg] + b[colg];
    }
  }
}

// ---------------- K10a: t2 = relu(h1@W1 + b1) ----------------
__global__ __launch_bounds__(256) void k_ffn1(const float* __restrict__ h1,
    const float* __restrict__ W, const float* __restrict__ bias, float* __restrict__ t2){
  __shared__ float Hs[128][36];
  __shared__ float Ws[16][132];
  int tid=threadIdx.x; int g0=blockIdx.x*32;
  { int row=tid>>3, kb=(tid&7)*16;
    #pragma unroll
    for (int j4=0;j4<4;++j4){
      float4 v = ld4(&h1[(size_t)(g0+row)*HD + kb + j4*4]);
      int c0=kb+j4*4;
      Hs[c0+0][row]=v.x; Hs[c0+1][row]=v.y; Hs[c0+2][row]=v.z; Hs[c0+3][row]=v.w;
    }
  }
  __syncthreads();
  int ty=tid>>5, tx=tid&31, wr=tid>>4, wc=(tid&15)*8;
  float acc[4][4];
  #pragma unroll
  for (int i=0;i<4;++i)
    #pragma unroll
    for (int j=0;j<4;++j) acc[i][j]=0.f;
  for (int kt=0;kt<8;++kt){
    *(float4*)&Ws[wr][wc]   = ld4(&W[(kt*16+wr)*HD + wc]);
    *(float4*)&Ws[wr][wc+4] = ld4(&W[(kt*16+wr)*HD + wc+4]);
    __syncthreads();
    #pragma unroll
    for (int kk=0;kk<16;++kk){
      float4 a = *(const float4*)&Hs[kt*16+kk][ty*4];
      float4 bb4 = *(const float4*)&Ws[kk][tx*4];
      float aa[4]={a.x,a.y,a.z,a.w};
      float bb[4]={bb4.x,bb4.y,bb4.z,bb4.w};
      #pragma unroll
      for (int i=0;i<4;++i)
        #pragma unroll
        for (int j=0;j<4;++j) acc[i][j]=fmaf(aa[i],bb[j],acc[i][j]);
    }
    __syncthreads();
  }
  #pragma unroll
  for (int i=0;i<4;++i){
    int r=ty*4+i;
    #pragma unroll
    for (int j=0;j<4;++j){
      int colg=tx*4+j;
      t2[(size_t)(g0+r)*HD + colg] = fmaxf(acc[i][j] + bias[colg], 0.f);
    }
  }
}

// ---------------- K10b: gobs = tanh(LN2(h1 + t2@W2 + b2)) ----------------
__global__ __launch_bounds__(256) void k_ln2(const float* __restrict__ h1,
    const float* __restrict__ t2, const float* __restrict__ W, const float* __restrict__ bias,
    const float* __restrict__ g, const float* __restrict__ b, float* __restrict__ gobs){
  __shared__ float Ts[128][36];
  __shared__ float Ws[16][132];
  __shared__ float Ss[32][132];
  __shared__ float mu_s[32], rs_s[32];
  int tid=threadIdx.x; int g0=blockIdx.x*32;
  { int row=tid>>3, kb=(tid&7)*16;
    #pragma unroll
    for (int j4=0;j4<4;++j4){
      float4 v = ld4(&t2[(size_t)(g0+row)*HD + kb + j4*4]);
      int c0=kb+j4*4;
      Ts[c0+0][row]=v.x; Ts[c0+1][row]=v.y; Ts[c0+2][row]=v.z; Ts[c0+3][row]=v.w;
    }
  }
  __syncthreads();
  int ty=tid>>5, tx=tid&31, wr=tid>>4, wc=(tid&15)*8;
  float acc[4][4];
  #pragma unroll
  for (int i=0;i<4;++i)
    #pragma unroll
    for (int j=0;j<4;++j) acc[i][j]=0.f;
  for (int kt=0;kt<8;++kt){
    *(float4*)&Ws[wr][wc]   = ld4(&W[(kt*16+wr)*HD + wc]);
    *(float4*)&Ws[wr][wc+4] = ld4(&W[(kt*16+wr)*HD + wc+4]);
    __syncthreads();
    #pragma unroll
    for (int kk=0;kk<16;++kk){
      float4 a = *(const float4*)&Ts[kt*16+kk][ty*4];
      float4 bb4 = *(const float4*)&Ws[kk][tx*4];
      float aa[4]={a.x,a.y,a.z,a.w};
      float bb[4]={bb4.x,bb4.y,bb4.z,bb4.w};
      #pragma unroll
      for (int i=0;i<4;++i)
        #pragma unroll
        for (int j=0;j<4;++j) acc[i][j]=fmaf(aa[i],bb[j],acc[i][j]);
    }
    __syncthreads();
  }
  #pragma unroll
  for (int i=0;i<4;++i){
    int r=ty*4+i;
    #pragma unroll
    for (int j=0;j<4;++j){
      int colg=tx*4+j;
      Ss[r][colg] = acc[i][j] + h1[(size_t)(g0+r)*HD + colg] + bias[colg];
    }
  }
  __syncthreads();
  if (tid<32){
    float mu=0.f;
    for (int k=0;k<HD;++k) mu += Ss[tid][k];
    mu *= (1.f/HD);
    float var=0.f;
    for (int k=0;k<HD;++k){ float d=Ss[tid][k]-mu; var += d*d; }
    var *= (1.f/HD);
    mu_s[tid]=mu; rs_s[tid]=rsqrtf(var+LN_EPS);
  }
  __syncthreads();
  #pragma unroll
  for (int i=0;i<4;++i){
    int r=ty*4+i;
    #pragma unroll
    for (int j=0;j<4;++j){
      int colg=tx*4+j;
      gobs[(size_t)(g0+r)*HD + colg] = tanhf((Ss[r][colg]-mu_s[r])*rs_s[r]*g[colg] + b[colg]);
    }
  }
}

// ---------------- K11: actor/value heads ----------------
__global__ __launch_bounds__(256) void k_head(
    const float* __restrict__ gobs, const int* __restrict__ ga,
    const float* __restrict__ intra,
    const float* __restrict__ aw1, const float* __restrict__ ab1,
    const float* __restrict__ aw2, const float* __restrict__ ab2,
    const float* __restrict__ vw1, const float* __restrict__ vb1,
    const float* __restrict__ vw2, const float* __restrict__ vb2,
    float* __restrict__ out_a, float* __restrict__ out_v){
  __shared__ float Af[256][36];
  __shared__ float Wst[16][132];
  __shared__ float HA[32][132];
  __shared__ float HV[32][132];
  int tid = threadIdx.x;
  int r0 = blockIdx.x*32;
  { int row = tid>>3, part = tid&7;
    int gr = r0 + row;
    int gidx = (gr<NN)? ga[gr] : 0;
    #pragma unroll
    for (int j4=0;j4<8;++j4){
      int cc = part*32 + j4*4;
      float4 vv = make_float4(0.f,0.f,0.f,0.f);
      if (gr<NN){
        vv = (cc<128)? ld4(&gobs[(size_t)gidx*HD + cc]) : ld4(&intra[(size_t)gr*HD + cc-128]);
      }
      Af[cc+0][row]=vv.x; Af[cc+1][row]=vv.y; Af[cc+2][row]=vv.z; Af[cc+3][row]=vv.w;
    }
  }
  __syncthreads();
  int ty=tid>>5, tx=tid&31, wr=tid>>4, wc=(tid&15)*8;
  float acc[4][4];
  // actor hidden
  #pragma unroll
  for (int i=0;i<4;++i)
    #pragma unroll
    for (int j=0;j<4;++j) acc[i][j]=0.f;
  for (int kt=0;kt<16;++kt){
    *(float4*)&Wst[wr][wc]   = ld4(&aw1[(kt*16+wr)*HD + wc]);
    *(float4*)&Wst[wr][wc+4] = ld4(&aw1[(kt*16+wr)*HD + wc+4]);
    __syncthreads();
    #pragma unroll
    for (int kk=0;kk<16;++kk){
      float4 a = *(const float4*)&Af[kt*16+kk][ty*4];
      float4 bb4 = *(const float4*)&Wst[kk][tx*4];
      float aa[4]={a.x,a.y,a.z,a.w};
      float bb[4]={bb4.x,bb4.y,bb4.z,bb4.w};
      #pragma unroll
      for (int i=0;i<4;++i)
        #pragma unroll
        for (int j=0;j<4;++j) acc[i][j]=fmaf(aa[i],bb[j],acc[i][j]);
    }
    __syncthreads();
  }
  #pragma unroll
  for (int i=0;i<4;++i)
    #pragma unroll
    for (int j=0;j<4;++j)
      HA[ty*4+i][tx*4+j] = tanhf(acc[i][j] + ab1[tx*4+j]);
  // value hidden
  #pragma unroll
  for (int i=0;i<4;++i)
    #pragma unroll
    for (int j=0;j<4;++j) acc[i][j]=0.f;
  for (int kt=0;kt<16;++kt){
    *(float4*)&Wst[wr][wc]   = ld4(&vw1[(kt*16+wr)*HD + wc]);
    *(float4*)&Wst[wr][wc+4] = ld4(&vw1[(kt*16+wr)*HD + wc+4]);
    __syncthreads();
    #pragma unroll
    for (int kk=0;kk<16;++kk){
      float4 a = *(const float4*)&Af[kt*16+kk][ty*4];
      float4 bb4 = *(const float4*)&Wst[kk][tx*4];
      float aa[4]={a.x,a.y,a.z,a.w};
      float bb[4]={bb4.x,bb4.y,bb4.z,bb4.w};
      #pragma unroll
      for (int i=0;i<4;++i)
        #pragma unroll
        for (int j=0;j<4;++j) acc[i][j]=fmaf(aa[i],bb[j],acc[i][j]);
    }
    __syncthreads();
  }
  #pragma unroll
  for (int i=0;i<4;++i)
    #pragma unroll
    for (int j=0;j<4;++j)
      HV[ty*4+i][tx*4+j] = tanhf(acc[i][j] + vb1[tx*4+j]);
  __syncthreads();
  if (tid < 32){
    int gr = r0 + tid;
    if (gr < NN){
      float lg[ACTD];
      #pragma unroll
      for (int cc=0;cc<ACTD;++cc) lg[cc]=ab2[cc];
      for (int k=0;k<HD;++k){
        float h = HA[tid][k];
        #pragma unroll
        for (int cc=0;cc<ACTD;++cc) lg[cc] = fmaf(h, aw2[k*ACTD+cc], lg[cc]);
      }
      float m = lg[0];
      #pragma unroll
      for (int cc=1;cc<ACTD;++cc) m = fmaxf(m, lg[cc]);
      float s=0.f;
      #pragma unroll
      for (int cc=0;cc<ACTD;++cc) s += __expf(lg[cc]-m);
      float ls = m + logf(s);
      #pragma unroll
      for (int cc=0;cc<ACTD;++cc) out_a[(size_t)gr*ACTD+cc] = lg[cc]-ls;
    }
  } else if (tid >= 64 && tid < 96){
    int r = tid-64;
    int gr = r0 + r;
    if (gr < NN){
      float s = vb2[0];
      for (int k=0;k<HD;++k) s = fmaf(HV[r][k], vw2[k], s);
      out_v[gr] = s;
    }
  }
}

extern "C" void kernel_launch(void* const* d_in, const int* in_sizes, int n_in,
                              void* d_out, int out_size, void* d_ws, size_t ws_size,
                              hipStream_t stream){
  const float* obs   = (const float*)d_in[0];
  const int*   ei    = (const int*)d_in[1];
  const int*   ga    = (const int*)d_in[2];
  const int*   core  = (const int*)d_in[3];
  const float* emb_w = (const float*)d_in[4];
  const float* emb_b = (const float*)d_in[5];
  const float* wl    = (const float*)d_in[6];
  const float* wrt   = (const float*)d_in[7];
  const float* att   = (const float*)d_in[8];
  const float* gbias = (const float*)d_in[9];
  const float* ainw  = (const float*)d_in[10];
  const float* ainb  = (const float*)d_in[11];
  const float* aoutw = (const float*)d_in[12];
  const float* aoutb = (const float*)d_in[13];
  const float* ln1g  = (const float*)d_in[14];
  const float* ln1b  = (const float*)d_in[15];
  const float* ln2g  = (const float*)d_in[16];
  const float* ln2b  = (const float*)d_in[17];
  const float* fw1   = (const float*)d_in[18];
  const float* fb1   = (const float*)d_in[19];
  const float* fw2   = (const float*)d_in[20];
  const float* fb2   = (const float*)d_in[21];
  const float* aw1   = (const float*)d_in[22];
  const float* ab1   = (const float*)d_in[23];
  const float* aw2   = (const float*)d_in[24];
  const float* ab2   = (const float*)d_in[25];
  const float* vw1   = (const float*)d_in[26];
  const float* vb1   = (const float*)d_in[27];
  const float* vw2   = (const float*)d_in[28];
  const float* vb2   = (const float*)d_in[29];

  char* wsp = (char*)d_ws;
  size_t off=0;
  auto alloc=[&](size_t bytes)->void*{
    void* p = wsp+off; off = (off+bytes+255) & ~(size_t)255; return p;
  };
  float* x      = (float*)alloc((size_t)NN*HD*4);   // x, later intra (in place of x)
  float* xl     = (float*)alloc((size_t)NN*HD*4);
  float* xr     = (float*)alloc((size_t)NN*HD*4);
  int*   col    = (int*)alloc((size_t)EE*4);
  int*   rowptr = (int*)alloc((size_t)(NN+1)*4);
  int*   cursor = (int*)alloc((size_t)NN*4);
  int*   chunks = (int*)alloc(256);
  float* cbuf   = (float*)alloc((size_t)GG*HD*4);
  float* qkv    = (float*)alloc((size_t)GG*384*4);
  float* sc     = (float*)alloc((size_t)NHEADS*GG*GG*4);
  float* ob     = (float*)alloc((size_t)GG*HD*4);
  float* h1     = (float*)alloc((size_t)GG*HD*4);
  float* t2     = (float*)alloc((size_t)GG*HD*4);
  float* gob    = (float*)alloc((size_t)GG*HD*4);

  float* out_a = (float*)d_out;
  float* out_v = out_a + (size_t)NN*ACTD;

  k_emb<<<782,256,0,stream>>>(obs, emb_w, emb_b, x);
  k_lift<<<782,256,0,stream>>>(x, wl, wrt, xl, xr);
  hipMemsetAsync(cursor, 0, (size_t)NN*4, stream);
  k_hist<<<EE/256,256,0,stream>>>(ei+EE, cursor);
  k_scanA<<<NCHUNKS,256,0,stream>>>(cursor, chunks);
  k_scanB<<<1,64,0,stream>>>(chunks, rowptr);
  k_scanC<<<NCHUNKS,256,0,stream>>>(cursor, chunks, rowptr);
  k_scatter<<<EE/256,256,0,stream>>>(ei, cursor, col);
  k_gat<<<NN/4,256,0,stream>>>(xl, xr, rowptr, col, att, gbias, x);   // intra -> x
  k_qkv<<<dim3(32,3),256,0,stream>>>(x, core, ainw, ainb, cbuf, qkv);
  k_scores<<<dim3(16,16,4),256,0,stream>>>(qkv, sc);
  k_softmax<<<1024,256,0,stream>>>(sc);
  k_av<<<dim3(16,4),256,0,stream>>>(sc, qkv, ob);
  k_ln1<<<32,256,0,stream>>>(cbuf, ob, aoutw, aoutb, ln1g, ln1b, h1);
  k_ffn1<<<32,256,0,stream>>>(h1, fw1, fb1, t2);
  k_ln2<<<32,256,0,stream>>>(h1, t2, fw2, fb2, ln2g, ln2b, gob);
  k_head<<<(NN+31)/32,256,0,stream>>>(gob, ga, x, aw1, ab1, aw2, ab2,
                                      vw1, vb1, vw2, vb2, out_a, out_v);
}

// Round 2
// 557.635 us; speedup vs baseline: 1.2870x; 1.2870x over previous
//
#include <hip/hip_runtime.h>
#include <hip/hip_bf16.h>
#include <math.h>

#define NN 50000
#define NPAD 50048
#define EE 800000
#define OBSD 256
#define HD 128
#define GG 1024
#define NHEADS 4
#define ACTD 10
#define LN_EPS 1e-5f
#define NCHUNKS 49   // ceil(50000/1024)

typedef short frag_t __attribute__((ext_vector_type(8)));
typedef float floatx4 __attribute__((ext_vector_type(4)));

__device__ __forceinline__ float4 ld4(const float* p){ return *(const float4*)p; }

__device__ __forceinline__ short f2bf(float f){
  unsigned u = __float_as_uint(f);
  u = (u + 0x7FFFu + ((u >> 16) & 1u)) >> 16;
  return (short)u;
}
__device__ __forceinline__ float bf2f(short s){
  return __uint_as_float(((unsigned)(unsigned short)s) << 16);
}
__device__ __forceinline__ unsigned pack2(float a, float b){
  return ((unsigned)(unsigned short)f2bf(a)) | (((unsigned)(unsigned short)f2bf(b)) << 16);
}

// ================= unified MFMA bf16 GEMM =================
// C[M, NT] = act(A[M,K] @ B[K,NT] + bias), A bf16 (or fp32 converted in staging),
// B pre-packed transposed bf16: Bt[n][k]. Output bf16.
// Tile 128x128, BK=64, 4 waves, each wave 64x64 (4x4 MFMA 16x16x32 tiles).
template<int K, int NT, int ACT, int HASB, int ACVT>
__global__ __launch_bounds__(256) void k_gemm(const void* __restrict__ Av,
    const short* __restrict__ Bt, const float* __restrict__ bias,
    short* __restrict__ C, int M){
  __shared__ short As[128*72];   // row-major [128 m][64 k], stride 72 (16B-aligned rows, 2-way banks)
  __shared__ short Bs[128*72];   // [128 n][64 k]
  int tid = threadIdx.x;
  int lane = tid & 63;
  int q = lane >> 4, l15 = lane & 15;
  int wv = tid >> 6;
  int m_off = (wv & 1) * 64, n_off = (wv >> 1) * 64;
  int row0 = blockIdx.x * 128;
  int col0 = blockIdx.y * 128;
  const float* A32 = (const float*)Av;
  const short* A16 = (const short*)Av;
  floatx4 acc[4][4];
  #pragma unroll
  for (int i=0;i<4;++i)
    #pragma unroll
    for (int j=0;j<4;++j) acc[i][j] = (floatx4)(0.f);
  for (int kt = 0; kt < K/64; ++kt){
    #pragma unroll
    for (int c = 0; c < 4; ++c){
      int li = tid + c*256;            // 0..1023: 128 rows x 8 chunks(16B)
      int r = li >> 3, off = (li & 7) * 8;
      int gk = kt*64 + off;
      int ar = row0 + r; if (ar >= M) ar = M - 1;   // clamp: no OOB reads on input tensors
      if (ACVT){
        const float* src = A32 + (size_t)ar * K + gk;
        float4 f0 = ld4(src);
        float4 f1 = ld4(src + 4);
        uint4 u;
        u.x = pack2(f0.x, f0.y); u.y = pack2(f0.z, f0.w);
        u.z = pack2(f1.x, f1.y); u.w = pack2(f1.z, f1.w);
        *(uint4*)&As[r*72 + off] = u;
      } else {
        *(uint4*)&As[r*72 + off] = *(const uint4*)(A16 + (size_t)ar * K + gk);
      }
      *(uint4*)&Bs[r*72 + off] = *(const uint4*)(Bt + (size_t)(col0 + r) * K + gk);
    }
    __syncthreads();
    #pragma unroll
    for (int ks = 0; ks < 64; ks += 32){
      frag_t af[4], bfr[4];
      #pragma unroll
      for (int i=0;i<4;++i){
        af[i]  = *(const frag_t*)&As[(m_off + i*16 + l15)*72 + ks + q*8];
        bfr[i] = *(const frag_t*)&Bs[(n_off + i*16 + l15)*72 + ks + q*8];
      }
      #pragma unroll
      for (int mi=0;mi<4;++mi)
        #pragma unroll
        for (int ni=0;ni<4;++ni)
          acc[mi][ni] = __builtin_amdgcn_mfma_f32_16x16x32_bf16(af[mi], bfr[ni], acc[mi][ni], 0, 0, 0);
    }
    __syncthreads();
  }
  #pragma unroll
  for (int mi=0;mi<4;++mi){
    #pragma unroll
    for (int r=0;r<4;++r){
      int grow = row0 + m_off + mi*16 + q*4 + r;
      if (grow < M){
        #pragma unroll
        for (int ni=0;ni<4;++ni){
          int gcol = col0 + n_off + ni*16 + l15;
          float vv = acc[mi][ni][r];
          if (HASB) vv += bias[gcol];
          if (ACT) vv = tanhf(vv);
          C[(size_t)grow*NT + gcol] = f2bf(vv);
        }
      }
    }
  }
}

// ================= weight packing (fp32 -> bf16 transposed) =================
__global__ __launch_bounds__(256) void k_pack(const float* __restrict__ embw,
    const float* __restrict__ wl, const float* __restrict__ wr,
    const float* __restrict__ aw1, const float* __restrict__ vw1,
    const float* __restrict__ ab1, const float* __restrict__ vb1,
    short* __restrict__ embWt, short* __restrict__ liftWt,
    short* __restrict__ headWt, float* __restrict__ biash){
  int n = blockIdx.x, k = threadIdx.x;   // 256 x 256
  if (n < 128) embWt[n*256 + k] = f2bf(embw[k*128 + n]);           // [128 n][256 k]
  if (k < 128)
    liftWt[n*128 + k] = (n < 128) ? f2bf(wl[k*128 + n]) : f2bf(wr[k*128 + (n-128)]);
  headWt[n*256 + k] = (n < 128) ? f2bf(aw1[k*128 + n]) : f2bf(vw1[k*128 + (n-128)]);
  if (k == 0) biash[n] = (n < 128) ? ab1[n] : vb1[n-128];
}

// ================= CSR build =================
__global__ __launch_bounds__(256) void k_hist(const int* __restrict__ dst, int* __restrict__ counts){
  int i = blockIdx.x*256 + threadIdx.x;
  if (i < EE) atomicAdd(&counts[dst[i]], 1);
}

__global__ __launch_bounds__(256) void k_scanA(const int* __restrict__ counts, int* __restrict__ chunks){
  __shared__ int red[256];
  int tid = threadIdx.x;
  int base = blockIdx.x*1024 + tid*4;
  int s = 0;
  #pragma unroll
  for (int j=0;j<4;++j) if (base+j < NN) s += counts[base+j];
  red[tid] = s; __syncthreads();
  for (int st=128; st>0; st>>=1){ if (tid<st) red[tid]+=red[tid+st]; __syncthreads(); }
  if (tid==0) chunks[blockIdx.x] = red[0];
}

__global__ __launch_bounds__(64) void k_scanB(int* __restrict__ chunks, int* __restrict__ rowptr){
  int lane = threadIdx.x;
  int v = (lane < NCHUNKS) ? chunks[lane] : 0;
  int orig = v;
  #pragma unroll
  for (int off=1; off<64; off<<=1){
    int t = __shfl_up(v, off, 64);
    if (lane >= off) v += t;
  }
  if (lane < NCHUNKS) chunks[lane] = v - orig;
  if (lane == 0) rowptr[NN] = EE;
}

__global__ __launch_bounds__(256) void k_scanC(int* __restrict__ cursor,
    const int* __restrict__ chunks, int* __restrict__ rowptr){
  __shared__ int sc[256];
  int tid = threadIdx.x;
  int base = blockIdx.x*1024 + tid*4;
  int c[4]; int ts = 0;
  #pragma unroll
  for (int j=0;j<4;++j){ c[j] = (base+j < NN) ? cursor[base+j] : 0; ts += c[j]; }
  sc[tid] = ts; __syncthreads();
  for (int off=1; off<256; off<<=1){
    int t = (tid >= off) ? sc[tid-off] : 0;
    __syncthreads();
    sc[tid] += t;
    __syncthreads();
  }
  int run = chunks[blockIdx.x] + sc[tid] - ts;
  #pragma unroll
  for (int j=0;j<4;++j){
    if (base+j < NN){ rowptr[base+j] = run; cursor[base+j] = run; run += c[j]; }
  }
}

__global__ __launch_bounds__(256) void k_scatter(const int* __restrict__ ei,
    int* __restrict__ cursor, int* __restrict__ col){
  int i = blockIdx.x*256 + threadIdx.x;
  if (i < EE){
    int s = ei[i], d = ei[EE+i];
    int p = atomicAdd(&cursor[d], 1);
    col[p] = s;
  }
}

// ================= GAT aggregate (bf16 xl/xr), one wave per node =================
__global__ __launch_bounds__(256) void k_gat(const short* __restrict__ xlr,
    const int* __restrict__ rowptr, const int* __restrict__ col,
    const float* __restrict__ att, const float* __restrict__ gbias,
    short* __restrict__ intra){
  int node = blockIdx.x*4 + (threadIdx.x >> 6);
  int lane = threadIdx.x & 63;
  unsigned uxr = *(const unsigned*)&xlr[(size_t)node*256 + 128 + 2*lane];
  float xrx = bf2f((short)(uxr & 0xffff)), xry = bf2f((short)(uxr >> 16));
  float2 att2 = *((const float2*)att + lane);
  unsigned uv = *(const unsigned*)&xlr[(size_t)node*256 + 2*lane];
  float vx = bf2f((short)(uv & 0xffff)), vy = bf2f((short)(uv >> 16));
  float ax = vx + xrx; ax = ax > 0.f ? ax : 0.2f*ax;
  float ay = vy + xry; ay = ay > 0.f ? ay : 0.2f*ay;
  float e = ax*att2.x + ay*att2.y;
  #pragma unroll
  for (int off=32; off>0; off>>=1) e += __shfl_xor(e, off, 64);
  float m = e, denom = 1.f;
  float accx = vx, accy = vy;
  int p1 = rowptr[node+1];
  for (int p = rowptr[node]; p < p1; ++p){
    int s = col[p];
    unsigned us = *(const unsigned*)&xlr[(size_t)s*256 + 2*lane];
    float sx = bf2f((short)(us & 0xffff)), sy = bf2f((short)(us >> 16));
    float bx = sx + xrx; bx = bx > 0.f ? bx : 0.2f*bx;
    float by = sy + xry; by = by > 0.f ? by : 0.2f*by;
    float es = bx*att2.x + by*att2.y;
    #pragma unroll
    for (int off=32; off>0; off>>=1) es += __shfl_xor(es, off, 64);
    float nm = fmaxf(m, es);
    float scl = __expf(m - nm);
    float ww  = __expf(es - nm);
    accx = accx*scl + ww*sx;
    accy = accy*scl + ww*sy;
    denom = denom*scl + ww;
    m = nm;
  }
  float2 gb = *((const float2*)gbias + lane);
  float inv = 1.f/denom;
  unsigned out = pack2(tanhf(accx*inv + gb.x), tanhf(accy*inv + gb.y));
  *(unsigned*)&intra[(size_t)node*128 + 2*lane] = out;
}

// ================= K5: c = intra[core]; qkv = c @ Win + b =================
__global__ __launch_bounds__(256) void k_qkv(const short* __restrict__ intra,
    const int* __restrict__ core, const float* __restrict__ W,
    const float* __restrict__ bias, float* __restrict__ c_out, float* __restrict__ qkv){
  __shared__ float Cs[128][36];
  __shared__ float Ws[16][132];
  int tid = threadIdx.x;
  int g0 = blockIdx.x*32;
  int cb = blockIdx.y;   // 0..2
  { int row = tid>>3, kb = (tid&7)*16;
    int src = core[g0+row];
    uint4 u0 = *(const uint4*)&intra[(size_t)src*128 + kb];
    uint4 u1 = *(const uint4*)&intra[(size_t)src*128 + kb + 8];
    float f[16];
    unsigned uu[8] = {u0.x,u0.y,u0.z,u0.w,u1.x,u1.y,u1.z,u1.w};
    #pragma unroll
    for (int j=0;j<8;++j){ f[2*j] = bf2f((short)(uu[j]&0xffff)); f[2*j+1] = bf2f((short)(uu[j]>>16)); }
    #pragma unroll
    for (int j=0;j<16;++j) Cs[kb+j][row] = f[j];
    if (cb == 0){
      #pragma unroll
      for (int j4=0;j4<4;++j4){
        float4 o = make_float4(f[j4*4], f[j4*4+1], f[j4*4+2], f[j4*4+3]);
        *(float4*)&c_out[(size_t)(g0+row)*HD + kb + j4*4] = o;
      }
    }
  }
  __syncthreads();
  int ty=tid>>5, tx=tid&31, wr=tid>>4, wc=(tid&15)*8;
  float acc[4][4];
  #pragma unroll
  for (int i=0;i<4;++i)
    #pragma unroll
    for (int j=0;j<4;++j) acc[i][j]=0.f;
  for (int kt=0;kt<8;++kt){
    *(float4*)&Ws[wr][wc]   = ld4(&W[(kt*16+wr)*384 + cb*128 + wc]);
    *(float4*)&Ws[wr][wc+4] = ld4(&W[(kt*16+wr)*384 + cb*128 + wc+4]);
    __syncthreads();
    #pragma unroll
    for (int kk=0;kk<16;++kk){
      float4 a = *(const float4*)&Cs[kt*16+kk][ty*4];
      float4 b = *(const float4*)&Ws[kk][tx*4];
      float aa[4]={a.x,a.y,a.z,a.w};
      float bb[4]={b.x,b.y,b.z,b.w};
      #pragma unroll
      for (int i=0;i<4;++i)
        #pragma unroll
        for (int j=0;j<4;++j) acc[i][j] = fmaf(aa[i], bb[j], acc[i][j]);
    }
    __syncthreads();
  }
  #pragma unroll
  for (int i=0;i<4;++i){
    int g = g0 + ty*4 + i;
    #pragma unroll
    for (int j=0;j<4;++j){
      int colg = cb*128 + tx*4 + j;
      qkv[(size_t)g*384 + colg] = acc[i][j] + bias[colg];
    }
  }
}

// ================= K6: scores =================
__global__ __launch_bounds__(256) void k_scores(const float* __restrict__ qkv, float* __restrict__ sc){
  __shared__ float Qs[32][68];
  __shared__ float Ks[32][68];
  int tid=threadIdx.x;
  int qt=blockIdx.x, kt=blockIdx.y, h=blockIdx.z;
  { int row=tid>>2, db=(tid&3)*8;
    float4 q0 = ld4(&qkv[(size_t)(qt*64+row)*384 + h*32 + db]);
    float4 q1 = ld4(&qkv[(size_t)(qt*64+row)*384 + h*32 + db + 4]);
    Qs[db+0][row]=q0.x; Qs[db+1][row]=q0.y; Qs[db+2][row]=q0.z; Qs[db+3][row]=q0.w;
    Qs[db+4][row]=q1.x; Qs[db+5][row]=q1.y; Qs[db+6][row]=q1.z; Qs[db+7][row]=q1.w;
    float4 k0 = ld4(&qkv[(size_t)(kt*64+row)*384 + 128 + h*32 + db]);
    float4 k1 = ld4(&qkv[(size_t)(kt*64+row)*384 + 128 + h*32 + db + 4]);
    Ks[db+0][row]=k0.x; Ks[db+1][row]=k0.y; Ks[db+2][row]=k0.z; Ks[db+3][row]=k0.w;
    Ks[db+4][row]=k1.x; Ks[db+5][row]=k1.y; Ks[db+6][row]=k1.z; Ks[db+7][row]=k1.w;
  }
  __syncthreads();
  int ty=tid>>4, tx=tid&15;
  float acc[4][4];
  #pragma unroll
  for (int i=0;i<4;++i)
    #pragma unroll
    for (int j=0;j<4;++j) acc[i][j]=0.f;
  #pragma unroll
  for (int d=0; d<32; ++d){
    float4 a = *(const float4*)&Qs[d][ty*4];
    float4 b = *(const float4*)&Ks[d][tx*4];
    float aa[4]={a.x,a.y,a.z,a.w};
    float bb[4]={b.x,b.y,b.z,b.w};
    #pragma unroll
    for (int i=0;i<4;++i)
      #pragma unroll
      for (int j=0;j<4;++j) acc[i][j] = fmaf(aa[i], bb[j], acc[i][j]);
  }
  const float scale = 0.17677669529663687f;
  #pragma unroll
  for (int i=0;i<4;++i){
    int row = qt*64+ty*4+i;
    float4 o = make_float4(acc[i][0]*scale, acc[i][1]*scale, acc[i][2]*scale, acc[i][3]*scale);
    *(float4*)&sc[((size_t)h*GG+row)*GG + kt*64 + tx*4] = o;
  }
}

// ================= K7: row softmax over 1024 =================
__global__ __launch_bounds__(256) void k_softmax(float* __restrict__ sc){
  int row = blockIdx.x*4 + (threadIdx.x>>6);
  int lane = threadIdx.x & 63;
  float* p = sc + (size_t)row*GG;
  float4 v[4];
  #pragma unroll
  for (int i=0;i<4;++i) v[i] = *(float4*)&p[lane*4 + i*256];
  float m = v[0].x;
  #pragma unroll
  for (int i=0;i<4;++i){
    m = fmaxf(m, v[i].x); m = fmaxf(m, v[i].y);
    m = fmaxf(m, v[i].z); m = fmaxf(m, v[i].w);
  }
  #pragma unroll
  for (int off=32; off>0; off>>=1) m = fmaxf(m, __shfl_xor(m, off, 64));
  float s=0.f;
  #pragma unroll
  for (int i=0;i<4;++i){
    v[i].x=__expf(v[i].x-m); v[i].y=__expf(v[i].y-m);
    v[i].z=__expf(v[i].z-m); v[i].w=__expf(v[i].w-m);
    s += v[i].x+v[i].y+v[i].z+v[i].w;
  }
  #pragma unroll
  for (int off=32; off>0; off>>=1) s += __shfl_xor(s, off, 64);
  float inv = 1.f/s;
  #pragma unroll
  for (int i=0;i<4;++i){
    v[i].x*=inv; v[i].y*=inv; v[i].z*=inv; v[i].w*=inv;
    *(float4*)&p[lane*4 + i*256] = v[i];
  }
}

// ================= K8: o = attn @ v =================
__global__ __launch_bounds__(256) void k_av(const float* __restrict__ sc,
    const float* __restrict__ qkv, float* __restrict__ ob){
  __shared__ float Ps[64][68];
  __shared__ float Vs[64][36];
  int tid=threadIdx.x;
  int qt=blockIdx.x, h=blockIdx.y;
  int ty=tid>>4, tx=tid&15;
  float acc[4][2];
  #pragma unroll
  for (int i=0;i<4;++i){ acc[i][0]=0.f; acc[i][1]=0.f; }
  for (int kt=0; kt<16; ++kt){
    { int row=tid>>2, kb=(tid&3)*16;
      const float* src = &sc[((size_t)h*GG + qt*64+row)*GG + kt*64 + kb];
      float4 a0=ld4(src), a1=ld4(src+4), a2=ld4(src+8), a3=ld4(src+12);
      Ps[kb+ 0][row]=a0.x; Ps[kb+ 1][row]=a0.y; Ps[kb+ 2][row]=a0.z; Ps[kb+ 3][row]=a0.w;
      Ps[kb+ 4][row]=a1.x; Ps[kb+ 5][row]=a1.y; Ps[kb+ 6][row]=a1.z; Ps[kb+ 7][row]=a1.w;
      Ps[kb+ 8][row]=a2.x; Ps[kb+ 9][row]=a2.y; Ps[kb+10][row]=a2.z; Ps[kb+11][row]=a2.w;
      Ps[kb+12][row]=a3.x; Ps[kb+13][row]=a3.y; Ps[kb+14][row]=a3.z; Ps[kb+15][row]=a3.w;
      int kk=tid>>2, db=(tid&3)*8;
      float4 v0 = ld4(&qkv[(size_t)(kt*64+kk)*384 + 256 + h*32 + db]);
      float4 v1 = ld4(&qkv[(size_t)(kt*64+kk)*384 + 256 + h*32 + db + 4]);
      *(float4*)&Vs[kk][db]   = v0;
      *(float4*)&Vs[kk][db+4] = v1;
    }
    __syncthreads();
    #pragma unroll
    for (int k=0;k<64;++k){
      float4 a = *(const float4*)&Ps[k][ty*4];
      float2 b = *(const float2*)&Vs[k][tx*2];
      acc[0][0]=fmaf(a.x,b.x,acc[0][0]); acc[0][1]=fmaf(a.x,b.y,acc[0][1]);
      acc[1][0]=fmaf(a.y,b.x,acc[1][0]); acc[1][1]=fmaf(a.y,b.y,acc[1][1]);
      acc[2][0]=fmaf(a.z,b.x,acc[2][0]); acc[2][1]=fmaf(a.z,b.y,acc[2][1]);
      acc[3][0]=fmaf(a.w,b.x,acc[3][0]); acc[3][1]=fmaf(a.w,b.y,acc[3][1]);
    }
    __syncthreads();
  }
  #pragma unroll
  for (int i=0;i<4;++i){
    float2 o2; o2.x=acc[i][0]; o2.y=acc[i][1];
    *(float2*)&ob[(size_t)(qt*64+ty*4+i)*HD + h*32 + tx*2] = o2;
  }
}

// ================= K9: h1 = LN1(c + o@Wout + b) =================
__global__ __launch_bounds__(256) void k_ln1(const float* __restrict__ c,
    const float* __restrict__ o, const float* __restrict__ W, const float* __restrict__ bias,
    const float* __restrict__ g, const float* __restrict__ b, float* __restrict__ h1){
  __shared__ float Os[128][36];
  __shared__ float Ws[16][132];
  __shared__ float Ss[32][132];
  __shared__ float mu_s[32], rs_s[32];
  int tid=threadIdx.x; int g0=blockIdx.x*32;
  { int row=tid>>3, kb=(tid&7)*16;
    #pragma unroll
    for (int j4=0;j4<4;++j4){
      float4 v = ld4(&o[(size_t)(g0+row)*HD + kb + j4*4]);
      int c0=kb+j4*4;
      Os[c0+0][row]=v.x; Os[c0+1][row]=v.y; Os[c0+2][row]=v.z; Os[c0+3][row]=v.w;
    }
  }
  __syncthreads();
  int ty=tid>>5, tx=tid&31, wr=tid>>4, wc=(tid&15)*8;
  float acc[4][4];
  #pragma unroll
  for (int i=0;i<4;++i)
    #pragma unroll
    for (int j=0;j<4;++j) acc[i][j]=0.f;
  for (int kt=0;kt<8;++kt){
    *(float4*)&Ws[wr][wc]   = ld4(&W[(kt*16+wr)*HD + wc]);
    *(float4*)&Ws[wr][wc+4] = ld4(&W[(kt*16+wr)*HD + wc+4]);
    __syncthreads();
    #pragma unroll
    for (int kk=0;kk<16;++kk){
      float4 a = *(const float4*)&Os[kt*16+kk][ty*4];
      float4 bb4 = *(const float4*)&Ws[kk][tx*4];
      float aa[4]={a.x,a.y,a.z,a.w};
      float bb[4]={bb4.x,bb4.y,bb4.z,bb4.w};
      #pragma unroll
      for (int i=0;i<4;++i)
        #pragma unroll
        for (int j=0;j<4;++j) acc[i][j]=fmaf(aa[i],bb[j],acc[i][j]);
    }
    __syncthreads();
  }
  #pragma unroll
  for (int i=0;i<4;++i){
    int r=ty*4+i;
    #pragma unroll
    for (int j=0;j<4;++j){
      int colg=tx*4+j;
      Ss[r][colg] = acc[i][j] + c[(size_t)(g0+r)*HD + colg] + bias[colg];
    }
  }
  __syncthreads();
  if (tid<32){
    float mu=0.f;
    for (int k=0;k<HD;++k) mu += Ss[tid][k];
    mu *= (1.f/HD);
    float var=0.f;
    for (int k=0;k<HD;++k){ float d=Ss[tid][k]-mu; var += d*d; }
    var *= (1.f/HD);
    mu_s[tid]=mu; rs_s[tid]=rsqrtf(var+LN_EPS);
  }
  __syncthreads();
  #pragma unroll
  for (int i=0;i<4;++i){
    int r=ty*4+i;
    #pragma unroll
    for (int j=0;j<4;++j){
      int colg=tx*4+j;
      h1[(size_t)(g0+r)*HD + colg] = (Ss[r][colg]-mu_s[r])*rs_s[r]*g[colg] + b[colg];
    }
  }
}

// ================= K10a: t2 = relu(h1@W1 + b1) =================
__global__ __launch_bounds__(256) void k_ffn1(const float* __restrict__ h1,
    const float* __restrict__ W, const float* __restrict__ bias, float* __restrict__ t2){
  __shared__ float Hs[128][36];
  __shared__ float Ws[16][132];
  int tid=threadIdx.x; int g0=blockIdx.x*32;
  { int row=tid>>3, kb=(tid&7)*16;
    #pragma unroll
    for (int j4=0;j4<4;++j4){
      float4 v = ld4(&h1[(size_t)(g0+row)*HD + kb + j4*4]);
      int c0=kb+j4*4;
      Hs[c0+0][row]=v.x; Hs[c0+1][row]=v.y; Hs[c0+2][row]=v.z; Hs[c0+3][row]=v.w;
    }
  }
  __syncthreads();
  int ty=tid>>5, tx=tid&31, wr=tid>>4, wc=(tid&15)*8;
  float acc[4][4];
  #pragma unroll
  for (int i=0;i<4;++i)
    #pragma unroll
    for (int j=0;j<4;++j) acc[i][j]=0.f;
  for (int kt=0;kt<8;++kt){
    *(float4*)&Ws[wr][wc]   = ld4(&W[(kt*16+wr)*HD + wc]);
    *(float4*)&Ws[wr][wc+4] = ld4(&W[(kt*16+wr)*HD + wc+4]);
    __syncthreads();
    #pragma unroll
    for (int kk=0;kk<16;++kk){
      float4 a = *(const float4*)&Hs[kt*16+kk][ty*4];
      float4 bb4 = *(const float4*)&Ws[kk][tx*4];
      float aa[4]={a.x,a.y,a.z,a.w};
      float bb[4]={bb4.x,bb4.y,bb4.z,bb4.w};
      #pragma unroll
      for (int i=0;i<4;++i)
        #pragma unroll
        for (int j=0;j<4;++j) acc[i][j]=fmaf(aa[i],bb[j],acc[i][j]);
    }
    __syncthreads();
  }
  #pragma unroll
  for (int i=0;i<4;++i){
    int r=ty*4+i;
    #pragma unroll
    for (int j=0;j<4;++j){
      int colg=tx*4+j;
      t2[(size_t)(g0+r)*HD + colg] = fmaxf(acc[i][j] + bias[colg], 0.f);
    }
  }
}

// ================= K10b: gobs = tanh(LN2(h1 + t2@W2 + b2)) =================
__global__ __launch_bounds__(256) void k_ln2(const float* __restrict__ h1,
    const float* __restrict__ t2, const float* __restrict__ W, const float* __restrict__ bias,
    const float* __restrict__ g, const float* __restrict__ b, float* __restrict__ gobs){
  __shared__ float Ts[128][36];
  __shared__ float Ws[16][132];
  __shared__ float Ss[32][132];
  __shared__ float mu_s[32], rs_s[32];
  int tid=threadIdx.x; int g0=blockIdx.x*32;
  { int row=tid>>3, kb=(tid&7)*16;
    #pragma unroll
    for (int j4=0;j4<4;++j4){
      float4 v = ld4(&t2[(size_t)(g0+row)*HD + kb + j4*4]);
      int c0=kb+j4*4;
      Ts[c0+0][row]=v.x; Ts[c0+1][row]=v.y; Ts[c0+2][row]=v.z; Ts[c0+3][row]=v.w;
    }
  }
  __syncthreads();
  int ty=tid>>5, tx=tid&31, wr=tid>>4, wc=(tid&15)*8;
  float acc[4][4];
  #pragma unroll
  for (int i=0;i<4;++i)
    #pragma unroll
    for (int j=0;j<4;++j) acc[i][j]=0.f;
  for (int kt=0;kt<8;++kt){
    *(float4*)&Ws[wr][wc]   = ld4(&W[(kt*16+wr)*HD + wc]);
    *(float4*)&Ws[wr][wc+4] = ld4(&W[(kt*16+wr)*HD + wc+4]);
    __syncthreads();
    #pragma unroll
    for (int kk=0;kk<16;++kk){
      float4 a = *(const float4*)&Ts[kt*16+kk][ty*4];
      float4 bb4 = *(const float4*)&Ws[kk][tx*4];
      float aa[4]={a.x,a.y,a.z,a.w};
      float bb[4]={bb4.x,bb4.y,bb4.z,bb4.w};
      #pragma unroll
      for (int i=0;i<4;++i)
        #pragma unroll
        for (int j=0;j<4;++j) acc[i][j]=fmaf(aa[i],bb[j],acc[i][j]);
    }
    __syncthreads();
  }
  #pragma unroll
  for (int i=0;i<4;++i){
    int r=ty*4+i;
    #pragma unroll
    for (int j=0;j<4;++j){
      int colg=tx*4+j;
      Ss[r][colg] = acc[i][j] + h1[(size_t)(g0+r)*HD + colg] + bias[colg];
    }
  }
  __syncthreads();
  if (tid<32){
    float mu=0.f;
    for (int k=0;k<HD;++k) mu += Ss[tid][k];
    mu *= (1.f/HD);
    float var=0.f;
    for (int k=0;k<HD;++k){ float d=Ss[tid][k]-mu; var += d*d; }
    var *= (1.f/HD);
    mu_s[tid]=mu; rs_s[tid]=rsqrtf(var+LN_EPS);
  }
  __syncthreads();
  #pragma unroll
  for (int i=0;i<4;++i){
    int r=ty*4+i;
    #pragma unroll
    for (int j=0;j<4;++j){
      int colg=tx*4+j;
      gobs[(size_t)(g0+r)*HD + colg] = tanhf((Ss[r][colg]-mu_s[r])*rs_s[r]*g[colg] + b[colg]);
    }
  }
}

// ================= after = [gobs[ga[r]] | intra[r]] in bf16 =================
__global__ __launch_bounds__(256) void k_after(const float* __restrict__ gobs,
    const short* __restrict__ intra, const int* __restrict__ ga, short* __restrict__ after){
  int row = blockIdx.x*8 + (threadIdx.x >> 5);
  int c0 = (threadIdx.x & 31) * 8;
  if (row >= NN) return;
  uint4 u;
  if (c0 < 128){
    int g = ga[row];
    float4 f0 = ld4(&gobs[(size_t)g*HD + c0]);
    float4 f1 = ld4(&gobs[(size_t)g*HD + c0 + 4]);
    u.x = pack2(f0.x, f0.y); u.y = pack2(f0.z, f0.w);
    u.z = pack2(f1.x, f1.y); u.w = pack2(f1.z, f1.w);
  } else {
    u = *(const uint4*)&intra[(size_t)row*HD + (c0 - 128)];
  }
  *(uint4*)&after[(size_t)row*256 + c0] = u;
}

// ================= output projection: logits + logsoftmax, value =================
__global__ __launch_bounds__(256) void k_outproj(const short* __restrict__ H,
    const float* __restrict__ aw2, const float* __restrict__ ab2,
    const float* __restrict__ vw2, const float* __restrict__ vb2,
    float* __restrict__ out_a, float* __restrict__ out_v){
  int r = blockIdx.x*256 + threadIdx.x;
  if (r >= NN) return;
  const short* hp = H + (size_t)r*256;
  float lg[ACTD];
  #pragma unroll
  for (int c=0;c<ACTD;++c) lg[c] = ab2[c];
  float vacc = vb2[0];
  for (int k8=0;k8<16;++k8){
    uint4 ua = *(const uint4*)(hp + k8*8);
    uint4 uv = *(const uint4*)(hp + 128 + k8*8);
    unsigned au[4] = {ua.x, ua.y, ua.z, ua.w};
    unsigned vu[4] = {uv.x, uv.y, uv.z, uv.w};
    #pragma unroll
    for (int j=0;j<4;++j){
      float a0 = bf2f((short)(au[j]&0xffff)), a1 = bf2f((short)(au[j]>>16));
      float v0 = bf2f((short)(vu[j]&0xffff)), v1 = bf2f((short)(vu[j]>>16));
      int k = k8*8 + j*2;
      #pragma unroll
      for (int c=0;c<ACTD;++c){
        lg[c] = fmaf(a0, aw2[k*ACTD+c], lg[c]);
        lg[c] = fmaf(a1, aw2[(k+1)*ACTD+c], lg[c]);
      }
      vacc = fmaf(v0, vw2[k], vacc);
      vacc = fmaf(v1, vw2[k+1], vacc);
    }
  }
  float m = lg[0];
  #pragma unroll
  for (int c=1;c<ACTD;++c) m = fmaxf(m, lg[c]);
  float s = 0.f;
  #pragma unroll
  for (int c=0;c<ACTD;++c) s += __expf(lg[c]-m);
  float ls = m + logf(s);
  #pragma unroll
  for (int c=0;c<ACTD;++c) out_a[(size_t)r*ACTD + c] = lg[c] - ls;
  out_v[r] = vacc;
}

extern "C" void kernel_launch(void* const* d_in, const int* in_sizes, int n_in,
                              void* d_out, int out_size, void* d_ws, size_t ws_size,
                              hipStream_t stream){
  const float* obs   = (const float*)d_in[0];
  const int*   ei    = (const int*)d_in[1];
  const int*   ga    = (const int*)d_in[2];
  const int*   core  = (const int*)d_in[3];
  const float* emb_w = (const float*)d_in[4];
  const float* emb_b = (const float*)d_in[5];
  const float* wl    = (const float*)d_in[6];
  const float* wrt   = (const float*)d_in[7];
  const float* att   = (const float*)d_in[8];
  const float* gbias = (const float*)d_in[9];
  const float* ainw  = (const float*)d_in[10];
  const float* ainb  = (const float*)d_in[11];
  const float* aoutw = (const float*)d_in[12];
  const float* aoutb = (const float*)d_in[13];
  const float* ln1g  = (const float*)d_in[14];
  const float* ln1b  = (const float*)d_in[15];
  const float* ln2g  = (const float*)d_in[16];
  const float* ln2b  = (const float*)d_in[17];
  const float* fw1   = (const float*)d_in[18];
  const float* fb1   = (const float*)d_in[19];
  const float* fw2   = (const float*)d_in[20];
  const float* fb2   = (const float*)d_in[21];
  const float* aw1   = (const float*)d_in[22];
  const float* ab1   = (const float*)d_in[23];
  const float* aw2   = (const float*)d_in[24];
  const float* ab2   = (const float*)d_in[25];
  const float* vw1   = (const float*)d_in[26];
  const float* vb1   = (const float*)d_in[27];
  const float* vw2   = (const float*)d_in[28];
  const float* vb2   = (const float*)d_in[29];

  char* wsp = (char*)d_ws;
  size_t off = 0;
  auto alloc = [&](size_t bytes)->void*{
    void* p = wsp + off; off = (off + bytes + 255) & ~(size_t)255; return p;
  };
  short* x_bf   = (short*)alloc((size_t)NPAD*HD*2);
  short* xlr    = (short*)alloc((size_t)NPAD*256*2);
  short* intra  = (short*)alloc((size_t)NPAD*HD*2);
  int*   col    = (int*)alloc((size_t)EE*4);
  int*   rowptr = (int*)alloc((size_t)(NN+1)*4);
  int*   cursor = (int*)alloc((size_t)NN*4);
  int*   chunks = (int*)alloc(256);
  float* cbuf   = (float*)alloc((size_t)GG*HD*4);
  float* qkv    = (float*)alloc((size_t)GG*384*4);
  float* sc     = (float*)alloc((size_t)NHEADS*GG*GG*4);
  float* ob     = (float*)alloc((size_t)GG*HD*4);
  float* h1     = (float*)alloc((size_t)GG*HD*4);
  float* t2     = (float*)alloc((size_t)GG*HD*4);
  float* gob    = (float*)alloc((size_t)GG*HD*4);
  short* after  = (short*)alloc((size_t)NPAD*256*2);
  short* Hbuf   = (short*)alloc((size_t)NPAD*256*2);
  short* embWt  = (short*)alloc((size_t)128*256*2);
  short* liftWt = (short*)alloc((size_t)256*128*2);
  short* headWt = (short*)alloc((size_t)256*256*2);
  float* biash  = (float*)alloc((size_t)256*4);

  float* out_a = (float*)d_out;
  float* out_v = out_a + (size_t)NN*ACTD;

  k_pack<<<256,256,0,stream>>>(emb_w, wl, wrt, aw1, vw1, ab1, vb1,
                               embWt, liftWt, headWt, biash);
  hipMemsetAsync(cursor, 0, (size_t)NN*4, stream);
  k_hist<<<EE/256,256,0,stream>>>(ei+EE, cursor);
  k_scanA<<<NCHUNKS,256,0,stream>>>(cursor, chunks);
  k_scanB<<<1,64,0,stream>>>(chunks, rowptr);
  k_scanC<<<NCHUNKS,256,0,stream>>>(cursor, chunks, rowptr);
  k_scatter<<<EE/256,256,0,stream>>>(ei, cursor, col);

  // x = tanh(obs @ emb_w + b)  (A fp32 converted in staging)
  k_gemm<256,128,1,1,1><<<dim3(391,1),256,0,stream>>>(obs, embWt, emb_b, x_bf, NN);
  // [xl | xr] = x @ [Wl | Wr]
  k_gemm<128,256,0,0,0><<<dim3(391,2),256,0,stream>>>(x_bf, liftWt, nullptr, xlr, NN);

  k_gat<<<NN/4,256,0,stream>>>(xlr, rowptr, col, att, gbias, intra);

  k_qkv<<<dim3(32,3),256,0,stream>>>(intra, core, ainw, ainb, cbuf, qkv);
  k_scores<<<dim3(16,16,4),256,0,stream>>>(qkv, sc);
  k_softmax<<<1024,256,0,stream>>>(sc);
  k_av<<<dim3(16,4),256,0,stream>>>(sc, qkv, ob);
  k_ln1<<<32,256,0,stream>>>(cbuf, ob, aoutw, aoutb, ln1g, ln1b, h1);
  k_ffn1<<<32,256,0,stream>>>(h1, fw1, fb1, t2);
  k_ln2<<<32,256,0,stream>>>(h1, t2, fw2, fb2, ln2g, ln2b, gob);

  k_after<<<6250,256,0,stream>>>(gob, intra, ga, after);
  // H = tanh(after @ [aw1|vw1] + [ab1|vb1])
  k_gemm<256,256,1,1,0><<<dim3(391,2),256,0,stream>>>(after, headWt, biash, Hbuf, NN);
  k_outproj<<<196,256,0,stream>>>(Hbuf, aw2, ab2, vw2, vb2, out_a, out_v);
}

// Round 3
// 447.947 us; speedup vs baseline: 1.6021x; 1.2449x over previous
//
#include <hip/hip_runtime.h>
#include <hip/hip_bf16.h>
#include <math.h>

#define NN 50000
#define NPAD 50048
#define EE 800000
#define OBSD 256
#define HD 128
#define GG 1024
#define NHEADS 4
#define ACTD 10
#define LN_EPS 1e-5f
#define NCHUNKS 49   // ceil(50000/1024)

typedef short frag_t __attribute__((ext_vector_type(8)));
typedef float floatx4 __attribute__((ext_vector_type(4)));

__device__ __forceinline__ float4 ld4(const float* p){ return *(const float4*)p; }

__device__ __forceinline__ short f2bf(float f){
  unsigned u = __float_as_uint(f);
  u = (u + 0x7FFFu + ((u >> 16) & 1u)) >> 16;
  return (short)u;
}
__device__ __forceinline__ float bf2f(short s){
  return __uint_as_float(((unsigned)(unsigned short)s) << 16);
}
__device__ __forceinline__ unsigned pack2(float a, float b){
  return ((unsigned)(unsigned short)f2bf(a)) | (((unsigned)(unsigned short)f2bf(b)) << 16);
}
__device__ __forceinline__ void unp8(uint4 u, float* f){
  unsigned a[4] = {u.x, u.y, u.z, u.w};
  #pragma unroll
  for (int j=0;j<4;++j){
    f[2*j]   = bf2f((short)(a[j] & 0xffff));
    f[2*j+1] = bf2f((short)(a[j] >> 16));
  }
}

// ================= unified MFMA bf16 GEMM (emb, lift) =================
template<int K, int NT, int ACT, int HASB, int ACVT>
__global__ __launch_bounds__(256) void k_gemm(const void* __restrict__ Av,
    const short* __restrict__ Bt, const float* __restrict__ bias,
    short* __restrict__ C, int M){
  __shared__ short As[128*72];
  __shared__ short Bs[128*72];
  int tid = threadIdx.x;
  int lane = tid & 63;
  int q = lane >> 4, l15 = lane & 15;
  int wv = tid >> 6;
  int m_off = (wv & 1) * 64, n_off = (wv >> 1) * 64;
  int row0 = blockIdx.x * 128;
  int col0 = blockIdx.y * 128;
  const float* A32 = (const float*)Av;
  const short* A16 = (const short*)Av;
  floatx4 acc[4][4];
  #pragma unroll
  for (int i=0;i<4;++i)
    #pragma unroll
    for (int j=0;j<4;++j) acc[i][j] = (floatx4)(0.f);
  for (int kt = 0; kt < K/64; ++kt){
    #pragma unroll
    for (int c = 0; c < 4; ++c){
      int li = tid + c*256;
      int r = li >> 3, off = (li & 7) * 8;
      int gk = kt*64 + off;
      int ar = row0 + r; if (ar >= M) ar = M - 1;
      if (ACVT){
        const float* src = A32 + (size_t)ar * K + gk;
        float4 f0 = ld4(src);
        float4 f1 = ld4(src + 4);
        uint4 u;
        u.x = pack2(f0.x, f0.y); u.y = pack2(f0.z, f0.w);
        u.z = pack2(f1.x, f1.y); u.w = pack2(f1.z, f1.w);
        *(uint4*)&As[r*72 + off] = u;
      } else {
        *(uint4*)&As[r*72 + off] = *(const uint4*)(A16 + (size_t)ar * K + gk);
      }
      *(uint4*)&Bs[r*72 + off] = *(const uint4*)(Bt + (size_t)(col0 + r) * K + gk);
    }
    __syncthreads();
    #pragma unroll
    for (int ks = 0; ks < 64; ks += 32){
      frag_t af[4], bfr[4];
      #pragma unroll
      for (int i=0;i<4;++i){
        af[i]  = *(const frag_t*)&As[(m_off + i*16 + l15)*72 + ks + q*8];
        bfr[i] = *(const frag_t*)&Bs[(n_off + i*16 + l15)*72 + ks + q*8];
      }
      #pragma unroll
      for (int mi=0;mi<4;++mi)
        #pragma unroll
        for (int ni=0;ni<4;++ni)
          acc[mi][ni] = __builtin_amdgcn_mfma_f32_16x16x32_bf16(af[mi], bfr[ni], acc[mi][ni], 0, 0, 0);
    }
    __syncthreads();
  }
  #pragma unroll
  for (int mi=0;mi<4;++mi){
    #pragma unroll
    for (int r=0;r<4;++r){
      int grow = row0 + m_off + mi*16 + q*4 + r;
      if (grow < M){
        #pragma unroll
        for (int ni=0;ni<4;++ni){
          int gcol = col0 + n_off + ni*16 + l15;
          float vv = acc[mi][ni][r];
          if (HASB) vv += bias[gcol];
          if (ACT) vv = tanhf(vv);
          C[(size_t)grow*NT + gcol] = f2bf(vv);
        }
      }
    }
  }
}

// ================= head GEMM with fused [gobs[ga]|intra] staging =================
__global__ __launch_bounds__(256) void k_hgemm(const float* __restrict__ gobs,
    const short* __restrict__ intra, const int* __restrict__ ga,
    const short* __restrict__ Bt, const float* __restrict__ bias,
    short* __restrict__ C, int M){
  __shared__ short As[128*72];
  __shared__ short Bs[128*72];
  int tid = threadIdx.x;
  int lane = tid & 63;
  int q = lane >> 4, l15 = lane & 15;
  int wv = tid >> 6;
  int m_off = (wv & 1) * 64, n_off = (wv >> 1) * 64;
  int row0 = blockIdx.x * 128;
  int col0 = blockIdx.y * 128;
  floatx4 acc[4][4];
  #pragma unroll
  for (int i=0;i<4;++i)
    #pragma unroll
    for (int j=0;j<4;++j) acc[i][j] = (floatx4)(0.f);
  for (int kt = 0; kt < 4; ++kt){
    #pragma unroll
    for (int c = 0; c < 4; ++c){
      int li = tid + c*256;
      int r = li >> 3, off = (li & 7) * 8;
      int gk = kt*64 + off;
      int ar = row0 + r; if (ar >= M) ar = M - 1;
      uint4 u;
      if (gk < 128){
        int gi = ga[ar];
        const float* src = gobs + (size_t)gi*HD + gk;
        float4 f0 = ld4(src);
        float4 f1 = ld4(src + 4);
        u.x = pack2(f0.x, f0.y); u.y = pack2(f0.z, f0.w);
        u.z = pack2(f1.x, f1.y); u.w = pack2(f1.z, f1.w);
      } else {
        u = *(const uint4*)(intra + (size_t)ar*HD + (gk - 128));
      }
      *(uint4*)&As[r*72 + off] = u;
      *(uint4*)&Bs[r*72 + off] = *(const uint4*)(Bt + (size_t)(col0 + r) * 256 + gk);
    }
    __syncthreads();
    #pragma unroll
    for (int ks = 0; ks < 64; ks += 32){
      frag_t af[4], bfr[4];
      #pragma unroll
      for (int i=0;i<4;++i){
        af[i]  = *(const frag_t*)&As[(m_off + i*16 + l15)*72 + ks + q*8];
        bfr[i] = *(const frag_t*)&Bs[(n_off + i*16 + l15)*72 + ks + q*8];
      }
      #pragma unroll
      for (int mi=0;mi<4;++mi)
        #pragma unroll
        for (int ni=0;ni<4;++ni)
          acc[mi][ni] = __builtin_amdgcn_mfma_f32_16x16x32_bf16(af[mi], bfr[ni], acc[mi][ni], 0, 0, 0);
    }
    __syncthreads();
  }
  #pragma unroll
  for (int mi=0;mi<4;++mi){
    #pragma unroll
    for (int r=0;r<4;++r){
      int grow = row0 + m_off + mi*16 + q*4 + r;
      if (grow < M){
        #pragma unroll
        for (int ni=0;ni<4;++ni){
          int gcol = col0 + n_off + ni*16 + l15;
          float vv = acc[mi][ni][r] + bias[gcol];
          C[(size_t)grow*256 + gcol] = f2bf(tanhf(vv));
        }
      }
    }
  }
}

// ================= weight packing =================
__global__ __launch_bounds__(256) void k_pack(const float* __restrict__ embw,
    const float* __restrict__ wl, const float* __restrict__ wr,
    const float* __restrict__ aw1, const float* __restrict__ vw1,
    const float* __restrict__ ab1, const float* __restrict__ vb1,
    short* __restrict__ embWt, short* __restrict__ liftWt,
    short* __restrict__ headWt, float* __restrict__ biash){
  int n = blockIdx.x, k = threadIdx.x;
  if (n < 128) embWt[n*256 + k] = f2bf(embw[k*128 + n]);
  if (k < 128)
    liftWt[n*128 + k] = (n < 128) ? f2bf(wl[k*128 + n]) : f2bf(wr[k*128 + (n-128)]);
  headWt[n*256 + k] = (n < 128) ? f2bf(aw1[k*128 + n]) : f2bf(vw1[k*128 + (n-128)]);
  if (k == 0) biash[n] = (n < 128) ? ab1[n] : vb1[n-128];
}

// ================= CSR build =================
__global__ __launch_bounds__(256) void k_hist(const int* __restrict__ dst, int* __restrict__ counts){
  int i = blockIdx.x*256 + threadIdx.x;
  if (i < EE) atomicAdd(&counts[dst[i]], 1);
}

__global__ __launch_bounds__(256) void k_scanA(const int* __restrict__ counts, int* __restrict__ chunks){
  __shared__ int red[256];
  int tid = threadIdx.x;
  int base = blockIdx.x*1024 + tid*4;
  int s = 0;
  #pragma unroll
  for (int j=0;j<4;++j) if (base+j < NN) s += counts[base+j];
  red[tid] = s; __syncthreads();
  for (int st=128; st>0; st>>=1){ if (tid<st) red[tid]+=red[tid+st]; __syncthreads(); }
  if (tid==0) chunks[blockIdx.x] = red[0];
}

__global__ __launch_bounds__(64) void k_scanB(int* __restrict__ chunks, int* __restrict__ rowptr){
  int lane = threadIdx.x;
  int v = (lane < NCHUNKS) ? chunks[lane] : 0;
  int orig = v;
  #pragma unroll
  for (int off=1; off<64; off<<=1){
    int t = __shfl_up(v, off, 64);
    if (lane >= off) v += t;
  }
  if (lane < NCHUNKS) chunks[lane] = v - orig;
  if (lane == 0) rowptr[NN] = EE;
}

__global__ __launch_bounds__(256) void k_scanC(int* __restrict__ cursor,
    const int* __restrict__ chunks, int* __restrict__ rowptr){
  __shared__ int sc[256];
  int tid = threadIdx.x;
  int base = blockIdx.x*1024 + tid*4;
  int c[4]; int ts = 0;
  #pragma unroll
  for (int j=0;j<4;++j){ c[j] = (base+j < NN) ? cursor[base+j] : 0; ts += c[j]; }
  sc[tid] = ts; __syncthreads();
  for (int off=1; off<256; off<<=1){
    int t = (tid >= off) ? sc[tid-off] : 0;
    __syncthreads();
    sc[tid] += t;
    __syncthreads();
  }
  int run = chunks[blockIdx.x] + sc[tid] - ts;
  #pragma unroll
  for (int j=0;j<4;++j){
    if (base+j < NN){ rowptr[base+j] = run; cursor[base+j] = run; run += c[j]; }
  }
}

__global__ __launch_bounds__(256) void k_scatter(const int* __restrict__ ei,
    int* __restrict__ cursor, int* __restrict__ col){
  int i = blockIdx.x*256 + threadIdx.x;
  if (i < EE){
    int s = ei[i], d = ei[EE+i];
    int p = atomicAdd(&cursor[d], 1);
    col[p] = s;
  }
}

// ================= GAT aggregate v2: wave per node, 4 edge-groups of 16 lanes =================
// group grp handles edge p0+grp; each lane covers 8 dims. Online softmax per group,
// 2-step butterfly merge across groups at the end.
__global__ __launch_bounds__(256) void k_gat(const short* __restrict__ xlr,
    const int* __restrict__ rowptr, const int* __restrict__ col,
    const float* __restrict__ att, const float* __restrict__ gbias,
    short* __restrict__ intra){
  int wv = threadIdx.x >> 6;
  int node = blockIdx.x*4 + wv;
  int lane = threadIdx.x & 63;
  int grp = lane >> 4;
  int t = lane & 15;
  const short* xrow = xlr + (size_t)node*256;
  float xr8[8], xs8[8], att8[8];
  unp8(*(const uint4*)(xrow + 128 + t*8), xr8);
  unp8(*(const uint4*)(xrow + t*8), xs8);
  { float4 a0 = ld4(att + t*8), a1 = ld4(att + t*8 + 4);
    att8[0]=a0.x; att8[1]=a0.y; att8[2]=a0.z; att8[3]=a0.w;
    att8[4]=a1.x; att8[5]=a1.y; att8[6]=a1.z; att8[7]=a1.w; }
  // self edge score
  float part = 0.f;
  #pragma unroll
  for (int d=0;d<8;++d){
    float z = xs8[d] + xr8[d];
    float lr = fmaxf(z, 0.f) + 0.2f*fminf(z, 0.f);
    part = fmaf(lr, att8[d], part);
  }
  part += __shfl_xor(part, 1, 64);
  part += __shfl_xor(part, 2, 64);
  part += __shfl_xor(part, 4, 64);
  part += __shfl_xor(part, 8, 64);
  float m, denom, acc[8];
  if (grp == 0){
    m = part; denom = 1.f;
    #pragma unroll
    for (int d=0;d<8;++d) acc[d] = xs8[d];
  } else {
    m = -1e30f; denom = 0.f;
    #pragma unroll
    for (int d=0;d<8;++d) acc[d] = 0.f;
  }
  int start = rowptr[node], end = rowptr[node+1];
  for (int p0 = start; p0 < end; p0 += 4){
    int p = p0 + grp;
    bool valid = p < end;
    int s = col[valid ? p : (end-1)];
    float v8[8];
    unp8(*(const uint4*)(xlr + (size_t)s*256 + t*8), v8);
    float pt = 0.f;
    #pragma unroll
    for (int d=0;d<8;++d){
      float z = v8[d] + xr8[d];
      float lr = fmaxf(z, 0.f) + 0.2f*fminf(z, 0.f);
      pt = fmaf(lr, att8[d], pt);
    }
    pt += __shfl_xor(pt, 1, 64);
    pt += __shfl_xor(pt, 2, 64);
    pt += __shfl_xor(pt, 4, 64);
    pt += __shfl_xor(pt, 8, 64);
    float nm = valid ? fmaxf(m, pt) : m;
    float scl = __expf(m - nm);
    float w = valid ? __expf(pt - nm) : 0.f;
    #pragma unroll
    for (int d=0;d<8;++d) acc[d] = acc[d]*scl + w*v8[d];
    denom = denom*scl + w;
    m = nm;
  }
  // merge 4 groups: butterfly over masks 16, 32
  #pragma unroll
  for (int mask = 16; mask <= 32; mask <<= 1){
    float om = __shfl_xor(m, mask, 64);
    float od = __shfl_xor(denom, mask, 64);
    float oa[8];
    #pragma unroll
    for (int d=0;d<8;++d) oa[d] = __shfl_xor(acc[d], mask, 64);
    float nm = fmaxf(m, om);
    float s1 = __expf(m - nm), s2 = __expf(om - nm);
    #pragma unroll
    for (int d=0;d<8;++d) acc[d] = acc[d]*s1 + oa[d]*s2;
    denom = denom*s1 + od*s2;
    m = nm;
  }
  if (grp == 0){
    float inv = 1.f / denom;
    float4 g0 = ld4(gbias + t*8), g1 = ld4(gbias + t*8 + 4);
    float gb[8] = {g0.x,g0.y,g0.z,g0.w,g1.x,g1.y,g1.z,g1.w};
    float o[8];
    #pragma unroll
    for (int d=0;d<8;++d) o[d] = tanhf(acc[d]*inv + gb[d]);
    uint4 u;
    u.x = pack2(o[0],o[1]); u.y = pack2(o[2],o[3]);
    u.z = pack2(o[4],o[5]); u.w = pack2(o[6],o[7]);
    *(uint4*)(intra + (size_t)node*128 + t*8) = u;
  }
}

// ================= row-wave: c = intra[core]; qkv = c @ Win + b =================
__global__ __launch_bounds__(256) void k_qkv(const short* __restrict__ intra,
    const int* __restrict__ core, const float* __restrict__ W,
    const float* __restrict__ bias, float* __restrict__ cbuf, float* __restrict__ qkv){
  __shared__ float sh[4][128];
  int wv = threadIdx.x >> 6, lane = threadIdx.x & 63;
  int r = blockIdx.x*4 + wv;
  int src = core[r];
  unsigned u = *(const unsigned*)(intra + (size_t)src*128 + lane*2);
  float c0 = bf2f((short)(u & 0xffff)), c1 = bf2f((short)(u >> 16));
  float2 cv; cv.x = c0; cv.y = c1;
  *(float2*)&cbuf[(size_t)r*128 + lane*2] = cv;
  sh[wv][lane*2] = c0; sh[wv][lane*2+1] = c1;
  __syncthreads();
  int cb = lane*6;
  float acc[6];
  #pragma unroll
  for (int j=0;j<6;++j) acc[j] = bias[cb+j];
  for (int k=0;k<128;++k){
    float xv = sh[wv][k];
    const float* wp = W + (size_t)k*384 + cb;
    float2 w0 = *(const float2*)wp, w1 = *(const float2*)(wp+2), w2 = *(const float2*)(wp+4);
    acc[0] = fmaf(xv, w0.x, acc[0]); acc[1] = fmaf(xv, w0.y, acc[1]);
    acc[2] = fmaf(xv, w1.x, acc[2]); acc[3] = fmaf(xv, w1.y, acc[3]);
    acc[4] = fmaf(xv, w2.x, acc[4]); acc[5] = fmaf(xv, w2.y, acc[5]);
  }
  float* qp = qkv + (size_t)r*384 + cb;
  float2 o0, o1, o2;
  o0.x=acc[0]; o0.y=acc[1]; o1.x=acc[2]; o1.y=acc[3]; o2.x=acc[4]; o2.y=acc[5];
  *(float2*)qp = o0; *(float2*)(qp+2) = o1; *(float2*)(qp+4) = o2;
}

// ================= K6: scores =================
__global__ __launch_bounds__(256) void k_scores(const float* __restrict__ qkv, float* __restrict__ sc){
  __shared__ float Qs[32][68];
  __shared__ float Ks[32][68];
  int tid=threadIdx.x;
  int qt=blockIdx.x, kt=blockIdx.y, h=blockIdx.z;
  { int row=tid>>2, db=(tid&3)*8;
    float4 q0 = ld4(&qkv[(size_t)(qt*64+row)*384 + h*32 + db]);
    float4 q1 = ld4(&qkv[(size_t)(qt*64+row)*384 + h*32 + db + 4]);
    Qs[db+0][row]=q0.x; Qs[db+1][row]=q0.y; Qs[db+2][row]=q0.z; Qs[db+3][row]=q0.w;
    Qs[db+4][row]=q1.x; Qs[db+5][row]=q1.y; Qs[db+6][row]=q1.z; Qs[db+7][row]=q1.w;
    float4 k0 = ld4(&qkv[(size_t)(kt*64+row)*384 + 128 + h*32 + db]);
    float4 k1 = ld4(&qkv[(size_t)(kt*64+row)*384 + 128 + h*32 + db + 4]);
    Ks[db+0][row]=k0.x; Ks[db+1][row]=k0.y; Ks[db+2][row]=k0.z; Ks[db+3][row]=k0.w;
    Ks[db+4][row]=k1.x; Ks[db+5][row]=k1.y; Ks[db+6][row]=k1.z; Ks[db+7][row]=k1.w;
  }
  __syncthreads();
  int ty=tid>>4, tx=tid&15;
  float acc[4][4];
  #pragma unroll
  for (int i=0;i<4;++i)
    #pragma unroll
    for (int j=0;j<4;++j) acc[i][j]=0.f;
  #pragma unroll
  for (int d=0; d<32; ++d){
    float4 a = *(const float4*)&Qs[d][ty*4];
    float4 b = *(const float4*)&Ks[d][tx*4];
    float aa[4]={a.x,a.y,a.z,a.w};
    float bb[4]={b.x,b.y,b.z,b.w};
    #pragma unroll
    for (int i=0;i<4;++i)
      #pragma unroll
      for (int j=0;j<4;++j) acc[i][j] = fmaf(aa[i], bb[j], acc[i][j]);
  }
  const float scale = 0.17677669529663687f;
  #pragma unroll
  for (int i=0;i<4;++i){
    int row = qt*64+ty*4+i;
    float4 o = make_float4(acc[i][0]*scale, acc[i][1]*scale, acc[i][2]*scale, acc[i][3]*scale);
    *(float4*)&sc[((size_t)h*GG+row)*GG + kt*64 + tx*4] = o;
  }
}

// ================= K7: row softmax over 1024 =================
__global__ __launch_bounds__(256) void k_softmax(float* __restrict__ sc){
  int row = blockIdx.x*4 + (threadIdx.x>>6);
  int lane = threadIdx.x & 63;
  float* p = sc + (size_t)row*GG;
  float4 v[4];
  #pragma unroll
  for (int i=0;i<4;++i) v[i] = *(float4*)&p[lane*4 + i*256];
  float m = v[0].x;
  #pragma unroll
  for (int i=0;i<4;++i){
    m = fmaxf(m, v[i].x); m = fmaxf(m, v[i].y);
    m = fmaxf(m, v[i].z); m = fmaxf(m, v[i].w);
  }
  #pragma unroll
  for (int off=32; off>0; off>>=1) m = fmaxf(m, __shfl_xor(m, off, 64));
  float s=0.f;
  #pragma unroll
  for (int i=0;i<4;++i){
    v[i].x=__expf(v[i].x-m); v[i].y=__expf(v[i].y-m);
    v[i].z=__expf(v[i].z-m); v[i].w=__expf(v[i].w-m);
    s += v[i].x+v[i].y+v[i].z+v[i].w;
  }
  #pragma unroll
  for (int off=32; off>0; off>>=1) s += __shfl_xor(s, off, 64);
  float inv = 1.f/s;
  #pragma unroll
  for (int i=0;i<4;++i){
    v[i].x*=inv; v[i].y*=inv; v[i].z*=inv; v[i].w*=inv;
    *(float4*)&p[lane*4 + i*256] = v[i];
  }
}

// ================= K8: o = attn @ v, split-K over 4 chunks, atomicAdd =================
__global__ __launch_bounds__(256) void k_av(const float* __restrict__ sc,
    const float* __restrict__ qkv, float* __restrict__ ob){
  __shared__ float Ps[64][68];
  __shared__ float Vs[64][36];
  int tid=threadIdx.x;
  int qt=blockIdx.x, h=blockIdx.y, kz=blockIdx.z;
  int ty=tid>>4, tx=tid&15;
  float acc[4][2];
  #pragma unroll
  for (int i=0;i<4;++i){ acc[i][0]=0.f; acc[i][1]=0.f; }
  for (int kt=kz*4; kt<kz*4+4; ++kt){
    { int row=tid>>2, kb=(tid&3)*16;
      const float* src = &sc[((size_t)h*GG + qt*64+row)*GG + kt*64 + kb];
      float4 a0=ld4(src), a1=ld4(src+4), a2=ld4(src+8), a3=ld4(src+12);
      Ps[kb+ 0][row]=a0.x; Ps[kb+ 1][row]=a0.y; Ps[kb+ 2][row]=a0.z; Ps[kb+ 3][row]=a0.w;
      Ps[kb+ 4][row]=a1.x; Ps[kb+ 5][row]=a1.y; Ps[kb+ 6][row]=a1.z; Ps[kb+ 7][row]=a1.w;
      Ps[kb+ 8][row]=a2.x; Ps[kb+ 9][row]=a2.y; Ps[kb+10][row]=a2.z; Ps[kb+11][row]=a2.w;
      Ps[kb+12][row]=a3.x; Ps[kb+13][row]=a3.y; Ps[kb+14][row]=a3.z; Ps[kb+15][row]=a3.w;
      int kk=tid>>2, db=(tid&3)*8;
      float4 v0 = ld4(&qkv[(size_t)(kt*64+kk)*384 + 256 + h*32 + db]);
      float4 v1 = ld4(&qkv[(size_t)(kt*64+kk)*384 + 256 + h*32 + db + 4]);
      *(float4*)&Vs[kk][db]   = v0;
      *(float4*)&Vs[kk][db+4] = v1;
    }
    __syncthreads();
    #pragma unroll
    for (int k=0;k<64;++k){
      float4 a = *(const float4*)&Ps[k][ty*4];
      float2 b = *(const float2*)&Vs[k][tx*2];
      acc[0][0]=fmaf(a.x,b.x,acc[0][0]); acc[0][1]=fmaf(a.x,b.y,acc[0][1]);
      acc[1][0]=fmaf(a.y,b.x,acc[1][0]); acc[1][1]=fmaf(a.y,b.y,acc[1][1]);
      acc[2][0]=fmaf(a.z,b.x,acc[2][0]); acc[2][1]=fmaf(a.z,b.y,acc[2][1]);
      acc[3][0]=fmaf(a.w,b.x,acc[3][0]); acc[3][1]=fmaf(a.w,b.y,acc[3][1]);
    }
    __syncthreads();
  }
  #pragma unroll
  for (int i=0;i<4;++i){
    float* dst = &ob[(size_t)(qt*64+ty*4+i)*HD + h*32 + tx*2];
    atomicAdd(dst,   acc[i][0]);
    atomicAdd(dst+1, acc[i][1]);
  }
}

// ================= row-wave: h1 = LN1(c + o@Wout + b) =================
__global__ __launch_bounds__(256) void k_ln1(const float* __restrict__ c,
    const float* __restrict__ o, const float* __restrict__ W, const float* __restrict__ bias,
    const float* __restrict__ g, const float* __restrict__ b, float* __restrict__ h1){
  __shared__ float sh[4][128];
  int wv = threadIdx.x >> 6, lane = threadIdx.x & 63;
  int r = blockIdx.x*4 + wv;
  int cb = lane*2;
  float2 ov = *(const float2*)&o[(size_t)r*128 + cb];
  sh[wv][cb] = ov.x; sh[wv][cb+1] = ov.y;
  __syncthreads();
  float a0 = 0.f, a1 = 0.f;
  for (int k=0;k<128;++k){
    float xv = sh[wv][k];
    float2 w = *(const float2*)&W[(size_t)k*128 + cb];
    a0 = fmaf(xv, w.x, a0); a1 = fmaf(xv, w.y, a1);
  }
  float2 cv = *(const float2*)&c[(size_t)r*128 + cb];
  float2 bv = *(const float2*)&bias[cb];
  float y0 = a0 + cv.x + bv.x, y1 = a1 + cv.y + bv.y;
  float s = y0 + y1;
  #pragma unroll
  for (int off=32; off>0; off>>=1) s += __shfl_xor(s, off, 64);
  float mu = s * (1.f/128.f);
  float d0 = y0 - mu, d1 = y1 - mu;
  float vv = d0*d0 + d1*d1;
  #pragma unroll
  for (int off=32; off>0; off>>=1) vv += __shfl_xor(vv, off, 64);
  float rs = rsqrtf(vv*(1.f/128.f) + LN_EPS);
  float2 gv = *(const float2*)&g[cb];
  float2 bb = *(const float2*)&b[cb];
  float2 out;
  out.x = d0*rs*gv.x + bb.x;
  out.y = d1*rs*gv.y + bb.y;
  *(float2*)&h1[(size_t)r*128 + cb] = out;
}

// ================= row-wave fused FFN: gobs = tanh(LN2(h1 + relu(h1@W1+b1)@W2 + b2)) =================
__global__ __launch_bounds__(256) void k_ffn(const float* __restrict__ h1,
    const float* __restrict__ W1, const float* __restrict__ b1,
    const float* __restrict__ W2, const float* __restrict__ b2,
    const float* __restrict__ g, const float* __restrict__ bb, float* __restrict__ gobs){
  __shared__ float sh[4][128];   // h1 row
  __shared__ float st[4][128];   // t row
  int wv = threadIdx.x >> 6, lane = threadIdx.x & 63;
  int r = blockIdx.x*4 + wv;
  int cb = lane*2;
  float2 hv = *(const float2*)&h1[(size_t)r*128 + cb];
  sh[wv][cb] = hv.x; sh[wv][cb+1] = hv.y;
  __syncthreads();
  float a0 = 0.f, a1 = 0.f;
  for (int k=0;k<128;++k){
    float xv = sh[wv][k];
    float2 w = *(const float2*)&W1[(size_t)k*128 + cb];
    a0 = fmaf(xv, w.x, a0); a1 = fmaf(xv, w.y, a1);
  }
  float2 b1v = *(const float2*)&b1[cb];
  st[wv][cb]   = fmaxf(a0 + b1v.x, 0.f);
  st[wv][cb+1] = fmaxf(a1 + b1v.y, 0.f);
  __syncthreads();
  a0 = 0.f; a1 = 0.f;
  for (int k=0;k<128;++k){
    float xv = st[wv][k];
    float2 w = *(const float2*)&W2[(size_t)k*128 + cb];
    a0 = fmaf(xv, w.x, a0); a1 = fmaf(xv, w.y, a1);
  }
  float2 b2v = *(const float2*)&b2[cb];
  float y0 = a0 + hv.x + b2v.x, y1 = a1 + hv.y + b2v.y;
  float s = y0 + y1;
  #pragma unroll
  for (int off=32; off>0; off>>=1) s += __shfl_xor(s, off, 64);
  float mu = s * (1.f/128.f);
  float d0 = y0 - mu, d1 = y1 - mu;
  float vv = d0*d0 + d1*d1;
  #pragma unroll
  for (int off=32; off>0; off>>=1) vv += __shfl_xor(vv, off, 64);
  float rs = rsqrtf(vv*(1.f/128.f) + LN_EPS);
  float2 gv = *(const float2*)&g[cb];
  float2 bv = *(const float2*)&bb[cb];
  float2 out;
  out.x = tanhf(d0*rs*gv.x + bv.x);
  out.y = tanhf(d1*rs*gv.y + bv.y);
  *(float2*)&gobs[(size_t)r*128 + cb] = out;
}

// ================= output projection =================
__global__ __launch_bounds__(256) void k_outproj(const short* __restrict__ H,
    const float* __restrict__ aw2, const float* __restrict__ ab2,
    const float* __restrict__ vw2, const float* __restrict__ vb2,
    float* __restrict__ out_a, float* __restrict__ out_v){
  int r = blockIdx.x*256 + threadIdx.x;
  if (r >= NN) return;
  const short* hp = H + (size_t)r*256;
  float lg[ACTD];
  #pragma unroll
  for (int c=0;c<ACTD;++c) lg[c] = ab2[c];
  float vacc = vb2[0];
  for (int k8=0;k8<16;++k8){
    uint4 ua = *(const uint4*)(hp + k8*8);
    uint4 uv = *(const uint4*)(hp + 128 + k8*8);
    unsigned au[4] = {ua.x, ua.y, ua.z, ua.w};
    unsigned vu[4] = {uv.x, uv.y, uv.z, uv.w};
    #pragma unroll
    for (int j=0;j<4;++j){
      float a0 = bf2f((short)(au[j]&0xffff)), a1 = bf2f((short)(au[j]>>16));
      float v0 = bf2f((short)(vu[j]&0xffff)), v1 = bf2f((short)(vu[j]>>16));
      int k = k8*8 + j*2;
      #pragma unroll
      for (int c=0;c<ACTD;++c){
        lg[c] = fmaf(a0, aw2[k*ACTD+c], lg[c]);
        lg[c] = fmaf(a1, aw2[(k+1)*ACTD+c], lg[c]);
      }
      vacc = fmaf(v0, vw2[k], vacc);
      vacc = fmaf(v1, vw2[k+1], vacc);
    }
  }
  float m = lg[0];
  #pragma unroll
  for (int c=1;c<ACTD;++c) m = fmaxf(m, lg[c]);
  float s = 0.f;
  #pragma unroll
  for (int c=0;c<ACTD;++c) s += __expf(lg[c]-m);
  float ls = m + logf(s);
  #pragma unroll
  for (int c=0;c<ACTD;++c) out_a[(size_t)r*ACTD + c] = lg[c] - ls;
  out_v[r] = vacc;
}

extern "C" void kernel_launch(void* const* d_in, const int* in_sizes, int n_in,
                              void* d_out, int out_size, void* d_ws, size_t ws_size,
                              hipStream_t stream){
  const float* obs   = (const float*)d_in[0];
  const int*   ei    = (const int*)d_in[1];
  const int*   ga    = (const int*)d_in[2];
  const int*   core  = (const int*)d_in[3];
  const float* emb_w = (const float*)d_in[4];
  const float* emb_b = (const float*)d_in[5];
  const float* wl    = (const float*)d_in[6];
  const float* wrt   = (const float*)d_in[7];
  const float* att   = (const float*)d_in[8];
  const float* gbias = (const float*)d_in[9];
  const float* ainw  = (const float*)d_in[10];
  const float* ainb  = (const float*)d_in[11];
  const float* aoutw = (const float*)d_in[12];
  const float* aoutb = (const float*)d_in[13];
  const float* ln1g  = (const float*)d_in[14];
  const float* ln1b  = (const float*)d_in[15];
  const float* ln2g  = (const float*)d_in[16];
  const float* ln2b  = (const float*)d_in[17];
  const float* fw1   = (const float*)d_in[18];
  const float* fb1   = (const float*)d_in[19];
  const float* fw2   = (const float*)d_in[20];
  const float* fb2   = (const float*)d_in[21];
  const float* aw1   = (const float*)d_in[22];
  const float* ab1   = (const float*)d_in[23];
  const float* aw2   = (const float*)d_in[24];
  const float* ab2   = (const float*)d_in[25];
  const float* vw1   = (const float*)d_in[26];
  const float* vb1   = (const float*)d_in[27];
  const float* vw2   = (const float*)d_in[28];
  const float* vb2   = (const float*)d_in[29];

  char* wsp = (char*)d_ws;
  size_t off = 0;
  auto alloc = [&](size_t bytes)->void*{
    void* p = wsp + off; off = (off + bytes + 255) & ~(size_t)255; return p;
  };
  short* x_bf   = (short*)alloc((size_t)NPAD*HD*2);
  short* xlr    = (short*)alloc((size_t)NPAD*256*2);
  short* intra  = (short*)alloc((size_t)NPAD*HD*2);
  int*   col    = (int*)alloc((size_t)EE*4);
  int*   rowptr = (int*)alloc((size_t)(NN+1)*4);
  int*   cursor = (int*)alloc((size_t)NN*4);
  int*   chunks = (int*)alloc(256);
  float* cbuf   = (float*)alloc((size_t)GG*HD*4);
  float* qkv    = (float*)alloc((size_t)GG*384*4);
  float* sc     = (float*)alloc((size_t)NHEADS*GG*GG*4);
  float* ob     = (float*)alloc((size_t)GG*HD*4);
  float* h1     = (float*)alloc((size_t)GG*HD*4);
  float* gob    = (float*)alloc((size_t)GG*HD*4);
  short* Hbuf   = (short*)alloc((size_t)NPAD*256*2);
  short* embWt  = (short*)alloc((size_t)128*256*2);
  short* liftWt = (short*)alloc((size_t)256*128*2);
  short* headWt = (short*)alloc((size_t)256*256*2);
  float* biash  = (float*)alloc((size_t)256*4);

  float* out_a = (float*)d_out;
  float* out_v = out_a + (size_t)NN*ACTD;

  k_pack<<<256,256,0,stream>>>(emb_w, wl, wrt, aw1, vw1, ab1, vb1,
                               embWt, liftWt, headWt, biash);
  hipMemsetAsync(cursor, 0, (size_t)NN*4, stream);
  hipMemsetAsync(ob, 0, (size_t)GG*HD*4, stream);
  k_hist<<<EE/256,256,0,stream>>>(ei+EE, cursor);
  k_scanA<<<NCHUNKS,256,0,stream>>>(cursor, chunks);
  k_scanB<<<1,64,0,stream>>>(chunks, rowptr);
  k_scanC<<<NCHUNKS,256,0,stream>>>(cursor, chunks, rowptr);
  k_scatter<<<EE/256,256,0,stream>>>(ei, cursor, col);

  k_gemm<256,128,1,1,1><<<dim3(391,1),256,0,stream>>>(obs, embWt, emb_b, x_bf, NN);
  k_gemm<128,256,0,0,0><<<dim3(391,2),256,0,stream>>>(x_bf, liftWt, nullptr, xlr, NN);

  k_gat<<<NN/4,256,0,stream>>>(xlr, rowptr, col, att, gbias, intra);

  k_qkv<<<256,256,0,stream>>>(intra, core, ainw, ainb, cbuf, qkv);
  k_scores<<<dim3(16,16,4),256,0,stream>>>(qkv, sc);
  k_softmax<<<1024,256,0,stream>>>(sc);
  k_av<<<dim3(16,4,4),256,0,stream>>>(sc, qkv, ob);
  k_ln1<<<256,256,0,stream>>>(cbuf, ob, aoutw, aoutb, ln1g, ln1b, h1);
  k_ffn<<<256,256,0,stream>>>(h1, fw1, fb1, fw2, fb2, ln2g, ln2b, gob);

  k_hgemm<<<dim3(391,2),256,0,stream>>>(gob, intra, ga, headWt, biash, Hbuf, NN);
  k_outproj<<<196,256,0,stream>>>(Hbuf, aw2, ab2, vw2, vb2, out_a, out_v);
}